// Round 1
// baseline (2243.834 us; speedup 1.0000x reference)
//
#include <hip/hip_runtime.h>

#define LAMBD 0.2f
#define KMAX 128

__device__ __forceinline__ float ssh(float v, float thr) {
    float a = fabsf(v) - thr;
    return a > 0.0f ? copysignf(a, v) : 0.0f;
}

__device__ __forceinline__ void fma4(float4& a, float s, const float4 b) {
    a.x += s * b.x; a.y += s * b.y; a.z += s * b.z; a.w += s * b.w;
}

// ---------------- Kernel 1: eta = 1 / sigma_max(D)^2 via power iteration on B = D D^T ----
__global__ __launch_bounds__(256) void eta_kernel(const float* __restrict__ Dg,
                                                  float* __restrict__ ws)
{
    __shared__ __align__(16) float Dc[256 * 68];  // Dc[m*68+i] = D[i][m], pad 68 for banks
    __shared__ __align__(16) float Bm[64 * 68];   // Bm[j*68+i] = B[j][i] (symmetric)
    __shared__ float vv[64];
    __shared__ float part[4 * 64];
    __shared__ float lamsh;

    const int t = threadIdx.x;
    for (int i = 0; i < 64; ++i)
        Dc[t * 68 + i] = Dg[i * 256 + t];          // coalesced global reads
    __syncthreads();

    // B = D D^T, 4x4 register tile per thread
    const int ti = t >> 4, tj = t & 15;
    float acc[4][4];
    #pragma unroll
    for (int r = 0; r < 4; ++r)
        #pragma unroll
        for (int c = 0; c < 4; ++c) acc[r][c] = 0.f;
    for (int mm = 0; mm < 256; ++mm) {
        const float4 A = *(const float4*)&Dc[mm * 68 + 4 * ti];
        const float4 Bv = *(const float4*)&Dc[mm * 68 + 4 * tj];
        const float Ae[4] = {A.x, A.y, A.z, A.w};
        const float Be[4] = {Bv.x, Bv.y, Bv.z, Bv.w};
        #pragma unroll
        for (int r = 0; r < 4; ++r)
            #pragma unroll
            for (int c = 0; c < 4; ++c)
                acc[r][c] += Ae[r] * Be[c];
    }
    #pragma unroll
    for (int r = 0; r < 4; ++r)
        #pragma unroll
        for (int c = 0; c < 4; ++c)
            Bm[(4 * ti + r) * 68 + (4 * tj + c)] = acc[r][c];
    if (t < 64) vv[t] = 0.125f;
    __syncthreads();

    for (int itp = 0; itp < 200; ++itp) {
        const int p = t >> 6, i = t & 63;
        float partial = 0.f;
        #pragma unroll
        for (int jj = 0; jj < 16; ++jj) {
            const int j = p * 16 + jj;
            partial += Bm[j * 68 + i] * vv[j];
        }
        part[p * 64 + i] = partial;
        __syncthreads();
        if (t < 64) {
            float nv = part[t] + part[64 + t] + part[128 + t] + part[192 + t];
            float n2 = nv * nv;
            for (int d = 1; d < 64; d <<= 1) n2 += __shfl_xor(n2, d);
            vv[t] = nv * rsqrtf(n2);
            if (t == 0) lamsh = n2;   // ||B v||^2 with v normalized -> lambda^2
        }
        __syncthreads();
    }
    if (t == 0) ws[0] = 1.0f / sqrtf(lamsh);   // eta = 1/lambda_max(B) = 1/sigma^2
}

// ---------------- Kernel 2: full Gram G = D^T D (256 x 256) ----------------
__global__ __launch_bounds__(256) void gram_kernel(const float* __restrict__ Dg,
                                                   float* __restrict__ Gfull)
{
    const int r = blockIdx.x, t = threadIdx.x;
    float acc = 0.f;
    #pragma unroll
    for (int i = 0; i < 64; ++i)
        acc += Dg[i * 256 + r] * Dg[i * 256 + t];
    Gfull[r * 256 + t] = acc;
}

// ---------------- Kernel 3: ISTA, 4 samples per workgroup, all in LDS/regs ----------------
__global__ __launch_bounds__(256) void ista_kernel(const float* __restrict__ xg,
                                                   const float* __restrict__ Dg,
                                                   const float* __restrict__ ws,
                                                   float* __restrict__ zbuf)
{
    __shared__ float4 d1[64 * 64];    // d1[c*64+l] = D[l][4c..4c+3]  (pass-1 layout)
    __shared__ float4 d2[16 * 256];   // d2[ci*256+m] = D[4ci..4ci+3][m] (pass-2 layout)
    __shared__ float4 z4[256];        // z4[m] = z[m][s=0..3]
    __shared__ float4 part[4 * 64];   // per-wave partial res
    __shared__ float4 res4[64];       // res[i][s]
    __shared__ float4 xs[64];         // x[i][s]
    __shared__ float4 wred[4];

    const int t = threadIdx.x;
    const int w = t >> 6, l = t & 63;
    const int s0 = blockIdx.x * 4;

    {
        const float4* Dg4 = (const float4*)Dg;
        #pragma unroll
        for (int cc = 0; cc < 16; ++cc) {
            const int c = w * 16 + cc;
            d1[c * 64 + l] = Dg4[l * 64 + c];
        }
        #pragma unroll
        for (int ci = 0; ci < 16; ++ci) {
            float4 v;
            v.x = Dg[(4 * ci + 0) * 256 + t];
            v.y = Dg[(4 * ci + 1) * 256 + t];
            v.z = Dg[(4 * ci + 2) * 256 + t];
            v.w = Dg[(4 * ci + 3) * 256 + t];
            d2[ci * 256 + t] = v;
        }
        if (t < 64) {
            float4 v;
            v.x = xg[(s0 + 0) * 64 + t];
            v.y = xg[(s0 + 1) * 64 + t];
            v.z = xg[(s0 + 2) * 64 + t];
            v.w = xg[(s0 + 3) * 64 + t];
            xs[t] = v;
        }
        z4[t] = make_float4(0.f, 0.f, 0.f, 0.f);
    }
    const float eta = ws[0];
    const float thr = LAMBD * eta;
    __syncthreads();

    float4 wdiff = make_float4(0.f, 0.f, 0.f, 0.f);
    for (int it = 0; it < 1001; ++it) {
        // pass 1: res-partial[l][s] += D[l][m] * z[m][s], m in wave's quarter
        float4 acc = make_float4(0.f, 0.f, 0.f, 0.f);
        #pragma unroll
        for (int cc = 0; cc < 16; ++cc) {
            const int cm = w * 16 + cc;
            const float4 d = d1[cm * 64 + l];
            fma4(acc, d.x, z4[4 * cm + 0]);
            fma4(acc, d.y, z4[4 * cm + 1]);
            fma4(acc, d.z, z4[4 * cm + 2]);
            fma4(acc, d.w, z4[4 * cm + 3]);
        }
        part[w * 64 + l] = acc;
        __syncthreads();
        if (t < 64) {
            const float4 p0 = part[t], p1 = part[64 + t], p2 = part[128 + t], p3 = part[192 + t];
            const float4 xv = xs[t];
            float4 r;
            r.x = p0.x + p1.x + p2.x + p3.x - xv.x;
            r.y = p0.y + p1.y + p2.y + p3.y - xv.y;
            r.z = p0.z + p1.z + p2.z + p3.z - xv.z;
            r.w = p0.w + p1.w + p2.w + p3.w - xv.w;
            res4[t] = r;
        }
        __syncthreads();
        // pass 2: g[m][s] = sum_i D[i][m] * res[i][s], thread t = m
        float4 g = make_float4(0.f, 0.f, 0.f, 0.f);
        #pragma unroll
        for (int ci = 0; ci < 16; ++ci) {
            const float4 dd = d2[ci * 256 + t];
            fma4(g, dd.x, res4[4 * ci + 0]);
            fma4(g, dd.y, res4[4 * ci + 1]);
            fma4(g, dd.z, res4[4 * ci + 2]);
            fma4(g, dd.w, res4[4 * ci + 3]);
        }
        const float4 zo = z4[t];
        float4 zn;
        zn.x = ssh(zo.x - eta * g.x, thr);
        zn.y = ssh(zo.y - eta * g.y, thr);
        zn.z = ssh(zo.z - eta * g.z, thr);
        zn.w = ssh(zo.w - eta * g.w, thr);
        const float ddx = zn.x - zo.x, ddy = zn.y - zo.y, ddz = zn.z - zo.z, ddw = zn.w - zo.w;
        wdiff.x += ddx * ddx; wdiff.y += ddy * ddy; wdiff.z += ddz * ddz; wdiff.w += ddw * ddw;
        z4[t] = zn;

        if ((it & 31) == 31) {
            float4 sred = wdiff;
            for (int d = 1; d < 64; d <<= 1) {
                sred.x += __shfl_xor(sred.x, d);
                sred.y += __shfl_xor(sred.y, d);
                sred.z += __shfl_xor(sred.z, d);
                sred.w += __shfl_xor(sred.w, d);
            }
            __syncthreads();
            if (l == 0) wred[w] = sred;
            __syncthreads();
            const float4 a0 = wred[0], a1 = wred[1], a2 = wred[2], a3 = wred[3];
            const float tx = a0.x + a1.x + a2.x + a3.x;
            const float ty = a0.y + a1.y + a2.y + a3.y;
            const float tz = a0.z + a1.z + a2.z + a3.z;
            const float tw = a0.w + a1.w + a2.w + a3.w;
            wdiff = make_float4(0.f, 0.f, 0.f, 0.f);
            if (tx < 1e-22f && ty < 1e-22f && tz < 1e-22f && tw < 1e-22f) break;
            __syncthreads();
        } else {
            __syncthreads();
        }
    }
    const float* zf = (const float*)&z4[t];
    #pragma unroll
    for (int s = 0; s < 4; ++s)
        zbuf[(s0 + s) * 256 + t] = zf[s];
}

// ---------------- Kernel 4: per-sample support solve (Cholesky) + y = w . alpha ----------
__global__ __launch_bounds__(64) void solve_kernel(const float* __restrict__ xg,
                                                   const float* __restrict__ Dg,
                                                   const float* __restrict__ wg,
                                                   const float* __restrict__ ws,
                                                   const float* __restrict__ zbuf,
                                                   float* __restrict__ out)
{
    __shared__ __align__(16) float Gm[KMAX * (KMAX + 1)];
    __shared__ int   idx[KMAX];
    __shared__ float sgn[KMAX];
    __shared__ float rhs[KMAX];
    __shared__ float sol[KMAX];
    __shared__ float xv[64];

    const int l = threadIdx.x;
    const int sample = blockIdx.x;

    const float4* zb4 = (const float4*)(zbuf + sample * 256);
    const float4 zz = zb4[l];
    const int c0 = zz.x != 0.f, c1 = zz.y != 0.f, c2 = zz.z != 0.f, c3 = zz.w != 0.f;
    const int cnt = c0 + c1 + c2 + c3;
    int scan = cnt;
    for (int d = 1; d < 64; d <<= 1) {
        const int v = __shfl_up(scan, d);
        if (l >= d) scan += v;
    }
    int o = scan - cnt;
    int k = __shfl(scan, 63);
    if (k > KMAX) k = KMAX;
    if (c0) { if (o < KMAX) { idx[o] = 4 * l + 0; sgn[o] = zz.x > 0.f ? 1.f : -1.f; } ++o; }
    if (c1) { if (o < KMAX) { idx[o] = 4 * l + 1; sgn[o] = zz.y > 0.f ? 1.f : -1.f; } ++o; }
    if (c2) { if (o < KMAX) { idx[o] = 4 * l + 2; sgn[o] = zz.z > 0.f ? 1.f : -1.f; } ++o; }
    if (c3) { if (o < KMAX) { idx[o] = 4 * l + 3; sgn[o] = zz.w > 0.f ? 1.f : -1.f; } ++o; }
    xv[l] = xg[sample * 64 + l];
    __syncthreads();

    if (k == 0) {
        if (l == 0) { out[sample * 2] = 0.f; out[sample * 2 + 1] = 0.f; }
        return;
    }

    const float* Gfull = ws + 256;
    for (int a = 0; a < k; ++a) {
        const int ra = idx[a];
        for (int b = l; b < k; b += 64)
            Gm[a * (KMAX + 1) + b] = Gfull[ra * 256 + idx[b]];
    }
    for (int a = l; a < k; a += 64) {
        const int ma = idx[a];
        float acc = 0.f;
        #pragma unroll
        for (int i = 0; i < 64; ++i)
            acc += Dg[i * 256 + ma] * xv[i];
        rhs[a] = acc - LAMBD * sgn[a];
    }
    __syncthreads();

    // Cholesky (lower) in place, stride KMAX+1 kills bank conflicts
    for (int j = 0; j < k; ++j) {
        const float Ljj = sqrtf(fmaxf(Gm[j * (KMAX + 1) + j], 1e-30f));
        const float inv = 1.0f / Ljj;
        if (l == 0) Gm[j * (KMAX + 1) + j] = Ljj;
        for (int a = j + 1 + l; a < k; a += 64)
            Gm[a * (KMAX + 1) + j] *= inv;
        __syncthreads();
        for (int b = j + 1; b < k; ++b) {
            const float Lbj = Gm[b * (KMAX + 1) + j];
            for (int a = b + l; a < k; a += 64)
                Gm[a * (KMAX + 1) + b] -= Gm[a * (KMAX + 1) + j] * Lbj;
        }
        __syncthreads();
    }
    // forward: L y = rhs
    for (int j = 0; j < k; ++j) {
        const float yj = rhs[j] / Gm[j * (KMAX + 1) + j];
        if (l == 0) sol[j] = yj;
        for (int a = j + 1 + l; a < k; a += 64)
            rhs[a] -= Gm[a * (KMAX + 1) + j] * yj;
        __syncthreads();
    }
    // backward: L^T x = y
    for (int j = k - 1; j >= 0; --j) {
        const float xj = sol[j] / Gm[j * (KMAX + 1) + j];
        if (l == 0) sol[j] = xj;
        for (int a = l; a < j; a += 64)
            sol[a] -= Gm[j * (KMAX + 1) + a] * xj;
        __syncthreads();
    }
    float acc = 0.f;
    for (int a = l; a < k; a += 64)
        acc += wg[idx[a]] * sol[a];
    for (int d = 1; d < 64; d <<= 1) acc += __shfl_xor(acc, d);
    if (l == 0) { out[sample * 2] = acc; out[sample * 2 + 1] = -acc; }
}

extern "C" void kernel_launch(void* const* d_in, const int* in_sizes, int n_in,
                              void* d_out, int out_size, void* d_ws, size_t ws_size,
                              hipStream_t stream) {
    const float* x = (const float*)d_in[0];   // (1024, 64)
    const float* D = (const float*)d_in[1];   // (64, 256)
    const float* w = (const float*)d_in[2];   // (256,)
    float* out = (float*)d_out;               // (1024, 2)
    float* ws  = (float*)d_ws;
    float* Gfull = ws + 256;                  // 256*256
    float* zbuf  = ws + 256 + 65536;          // 1024*256

    eta_kernel<<<1, 256, 0, stream>>>(D, ws);
    gram_kernel<<<256, 256, 0, stream>>>(D, Gfull);
    ista_kernel<<<256, 256, 0, stream>>>(x, D, ws, zbuf);
    solve_kernel<<<1024, 64, 0, stream>>>(x, D, w, ws, zbuf, out);
}

// Round 2
// 2138.221 us; speedup vs baseline: 1.0494x; 1.0494x over previous
//
#include <hip/hip_runtime.h>

#define LAMBD 0.2f
#define KMAX 128

__device__ __forceinline__ float ssh(float v, float thr) {
    float a = fabsf(v) - thr;
    return a > 0.0f ? copysignf(a, v) : 0.0f;
}

__device__ __forceinline__ float rlane(float v, int lane) {
    return __int_as_float(__builtin_amdgcn_readlane(__float_as_int(v), lane));
}

// ---------------- Kernel 1: eta = 1 / sigma_max(D)^2 via power iteration on B = D D^T ----
__global__ __launch_bounds__(256) void eta_kernel(const float* __restrict__ Dg,
                                                  float* __restrict__ ws)
{
    __shared__ __align__(16) float Dc[256 * 68];  // Dc[m*68+i] = D[i][m], pad 68 for banks
    __shared__ __align__(16) float Bm[64 * 68];   // Bm[j*68+i] = B[j][i] (symmetric)
    __shared__ float vv[64];
    __shared__ float part[4 * 64];
    __shared__ float lamsh;

    const int t = threadIdx.x;
    for (int i = 0; i < 64; ++i)
        Dc[t * 68 + i] = Dg[i * 256 + t];          // coalesced global reads
    __syncthreads();

    // B = D D^T, 4x4 register tile per thread
    const int ti = t >> 4, tj = t & 15;
    float acc[4][4];
    #pragma unroll
    for (int r = 0; r < 4; ++r)
        #pragma unroll
        for (int c = 0; c < 4; ++c) acc[r][c] = 0.f;
    for (int mm = 0; mm < 256; ++mm) {
        const float4 A = *(const float4*)&Dc[mm * 68 + 4 * ti];
        const float4 Bv = *(const float4*)&Dc[mm * 68 + 4 * tj];
        const float Ae[4] = {A.x, A.y, A.z, A.w};
        const float Be[4] = {Bv.x, Bv.y, Bv.z, Bv.w};
        #pragma unroll
        for (int r = 0; r < 4; ++r)
            #pragma unroll
            for (int c = 0; c < 4; ++c)
                acc[r][c] += Ae[r] * Be[c];
    }
    #pragma unroll
    for (int r = 0; r < 4; ++r)
        #pragma unroll
        for (int c = 0; c < 4; ++c)
            Bm[(4 * ti + r) * 68 + (4 * tj + c)] = acc[r][c];
    if (t < 64) vv[t] = 0.125f;
    __syncthreads();

    for (int itp = 0; itp < 200; ++itp) {
        const int p = t >> 6, i = t & 63;
        float partial = 0.f;
        #pragma unroll
        for (int jj = 0; jj < 16; ++jj) {
            const int j = p * 16 + jj;
            partial += Bm[j * 68 + i] * vv[j];
        }
        part[p * 64 + i] = partial;
        __syncthreads();
        if (t < 64) {
            float nv = part[t] + part[64 + t] + part[128 + t] + part[192 + t];
            float n2 = nv * nv;
            for (int d = 1; d < 64; d <<= 1) n2 += __shfl_xor(n2, d);
            vv[t] = nv * rsqrtf(n2);
            if (t == 0) lamsh = n2;   // ||B v||^2 with v normalized -> lambda^2
        }
        __syncthreads();
    }
    if (t == 0) ws[0] = 1.0f / sqrtf(lamsh);   // eta = 1/lambda_max(B) = 1/sigma^2
}

// ---------------- Kernel 2: full Gram G = D^T D (256 x 256) ----------------
__global__ __launch_bounds__(256) void gram_kernel(const float* __restrict__ Dg,
                                                   float* __restrict__ Gfull)
{
    const int r = blockIdx.x, t = threadIdx.x;
    float acc = 0.f;
    #pragma unroll
    for (int i = 0; i < 64; ++i)
        acc += Dg[i * 256 + r] * Dg[i * 256 + t];
    Gfull[r * 256 + t] = acc;
}

// ---------------- Kernel 3: ISTA, 4 samples per workgroup ----------------
// Pass-1 D tile lives in VGPRs; z / res are gathered lane-distinct from LDS and
// redistributed with v_readlane (VALU) instead of LDS broadcast reads.
__global__ __launch_bounds__(256, 1) void ista_kernel(const float* __restrict__ xg,
                                                      const float* __restrict__ Dg,
                                                      const float* __restrict__ ws,
                                                      float* __restrict__ zbuf)
{
    __shared__ float4 d2[16 * 256];   // d2[ci*256+m] = D[4ci..4ci+3][m] (pass-2 layout)
    __shared__ float4 z4[256];        // z4[m] = z[m][s=0..3]
    __shared__ float4 part[4 * 64];   // per-wave partial res
    __shared__ float4 res4[64];       // res[i][s]
    __shared__ float4 xs[64];         // x[i][s]
    __shared__ float4 wred[4];

    const int t = threadIdx.x;
    const int w = t >> 6, l = t & 63;
    const int s0 = blockIdx.x * 4;

    // pass-1 D tile in registers: lane l of wave w holds D[l][64w .. 64w+63]
    float4 dreg[16];
    #pragma unroll
    for (int c = 0; c < 16; ++c)
        dreg[c] = *(const float4*)&Dg[l * 256 + 64 * w + 4 * c];

    {
        #pragma unroll
        for (int ci = 0; ci < 16; ++ci) {
            float4 v;
            v.x = Dg[(4 * ci + 0) * 256 + t];
            v.y = Dg[(4 * ci + 1) * 256 + t];
            v.z = Dg[(4 * ci + 2) * 256 + t];
            v.w = Dg[(4 * ci + 3) * 256 + t];
            d2[ci * 256 + t] = v;
        }
        if (t < 64) {
            float4 v;
            v.x = xg[(s0 + 0) * 64 + t];
            v.y = xg[(s0 + 1) * 64 + t];
            v.z = xg[(s0 + 2) * 64 + t];
            v.w = xg[(s0 + 3) * 64 + t];
            xs[t] = v;
        }
        z4[t] = make_float4(0.f, 0.f, 0.f, 0.f);
    }
    const float eta = ws[0];
    const float thr = LAMBD * eta;
    __syncthreads();

    float4 wdiff = make_float4(0.f, 0.f, 0.f, 0.f);
    for (int it = 0; it < 1001; ++it) {
        // ---- pass 1: res-partial[l][s] += D[l][m] * z[m][s], m in wave's quarter.
        // z gathered lane-distinct (1 ds_read_b128), redistributed via readlane.
        const float4 zq = z4[64 * w + l];
        float4 acc = make_float4(0.f, 0.f, 0.f, 0.f);
        #pragma unroll
        for (int c = 0; c < 16; ++c) {
            const float4 d = dreg[c];
            const float de[4] = {d.x, d.y, d.z, d.w};
            #pragma unroll
            for (int j = 0; j < 4; ++j) {
                const int src = 4 * c + j;
                const float dj = de[j];
                acc.x += dj * rlane(zq.x, src);
                acc.y += dj * rlane(zq.y, src);
                acc.z += dj * rlane(zq.z, src);
                acc.w += dj * rlane(zq.w, src);
            }
        }
        part[w * 64 + l] = acc;
        __syncthreads();
        if (t < 64) {
            const float4 p0 = part[t], p1 = part[64 + t], p2 = part[128 + t], p3 = part[192 + t];
            const float4 xv = xs[t];
            float4 r;
            r.x = p0.x + p1.x + p2.x + p3.x - xv.x;
            r.y = p0.y + p1.y + p2.y + p3.y - xv.y;
            r.z = p0.z + p1.z + p2.z + p3.z - xv.z;
            r.w = p0.w + p1.w + p2.w + p3.w - xv.w;
            res4[t] = r;
        }
        __syncthreads();
        // ---- pass 2: g[m][s] = sum_i D[i][m] * res[i][s], thread t = m.
        // res gathered lane-distinct (1 ds_read_b128), redistributed via readlane.
        const float4 rq = res4[l];
        float4 g = make_float4(0.f, 0.f, 0.f, 0.f);
        #pragma unroll
        for (int ci = 0; ci < 16; ++ci) {
            const float4 dd = d2[ci * 256 + t];
            const float de[4] = {dd.x, dd.y, dd.z, dd.w};
            #pragma unroll
            for (int j = 0; j < 4; ++j) {
                const int i = 4 * ci + j;
                const float dj = de[j];
                g.x += dj * rlane(rq.x, i);
                g.y += dj * rlane(rq.y, i);
                g.z += dj * rlane(rq.z, i);
                g.w += dj * rlane(rq.w, i);
            }
        }
        const float4 zo = z4[t];
        float4 zn;
        zn.x = ssh(zo.x - eta * g.x, thr);
        zn.y = ssh(zo.y - eta * g.y, thr);
        zn.z = ssh(zo.z - eta * g.z, thr);
        zn.w = ssh(zo.w - eta * g.w, thr);
        const float ddx = zn.x - zo.x, ddy = zn.y - zo.y, ddz = zn.z - zo.z, ddw = zn.w - zo.w;
        wdiff.x += ddx * ddx; wdiff.y += ddy * ddy; wdiff.z += ddz * ddz; wdiff.w += ddw * ddw;
        z4[t] = zn;

        if ((it & 31) == 31) {
            float4 sred = wdiff;
            for (int d = 1; d < 64; d <<= 1) {
                sred.x += __shfl_xor(sred.x, d);
                sred.y += __shfl_xor(sred.y, d);
                sred.z += __shfl_xor(sred.z, d);
                sred.w += __shfl_xor(sred.w, d);
            }
            __syncthreads();
            if (l == 0) wred[w] = sred;
            __syncthreads();
            const float4 a0 = wred[0], a1 = wred[1], a2 = wred[2], a3 = wred[3];
            const float tx = a0.x + a1.x + a2.x + a3.x;
            const float ty = a0.y + a1.y + a2.y + a3.y;
            const float tz = a0.z + a1.z + a2.z + a3.z;
            const float tw = a0.w + a1.w + a2.w + a3.w;
            wdiff = make_float4(0.f, 0.f, 0.f, 0.f);
            if (tx < 1e-22f && ty < 1e-22f && tz < 1e-22f && tw < 1e-22f) break;
            __syncthreads();
        } else {
            __syncthreads();
        }
    }
    const float* zf = (const float*)&z4[t];
    #pragma unroll
    for (int s = 0; s < 4; ++s)
        zbuf[(s0 + s) * 256 + t] = zf[s];
}

// ---------------- Kernel 4: per-sample support solve (Cholesky) + y = w . alpha ----------
__global__ __launch_bounds__(64) void solve_kernel(const float* __restrict__ xg,
                                                   const float* __restrict__ Dg,
                                                   const float* __restrict__ wg,
                                                   const float* __restrict__ ws,
                                                   const float* __restrict__ zbuf,
                                                   float* __restrict__ out)
{
    __shared__ __align__(16) float Gm[KMAX * (KMAX + 1)];
    __shared__ int   idx[KMAX];
    __shared__ float sgn[KMAX];
    __shared__ float rhs[KMAX];
    __shared__ float sol[KMAX];
    __shared__ float xv[64];

    const int l = threadIdx.x;
    const int sample = blockIdx.x;

    const float4* zb4 = (const float4*)(zbuf + sample * 256);
    const float4 zz = zb4[l];
    const int c0 = zz.x != 0.f, c1 = zz.y != 0.f, c2 = zz.z != 0.f, c3 = zz.w != 0.f;
    const int cnt = c0 + c1 + c2 + c3;
    int scan = cnt;
    for (int d = 1; d < 64; d <<= 1) {
        const int v = __shfl_up(scan, d);
        if (l >= d) scan += v;
    }
    int o = scan - cnt;
    int k = __shfl(scan, 63);
    if (k > KMAX) k = KMAX;
    if (c0) { if (o < KMAX) { idx[o] = 4 * l + 0; sgn[o] = zz.x > 0.f ? 1.f : -1.f; } ++o; }
    if (c1) { if (o < KMAX) { idx[o] = 4 * l + 1; sgn[o] = zz.y > 0.f ? 1.f : -1.f; } ++o; }
    if (c2) { if (o < KMAX) { idx[o] = 4 * l + 2; sgn[o] = zz.z > 0.f ? 1.f : -1.f; } ++o; }
    if (c3) { if (o < KMAX) { idx[o] = 4 * l + 3; sgn[o] = zz.w > 0.f ? 1.f : -1.f; } ++o; }
    xv[l] = xg[sample * 64 + l];
    __syncthreads();

    if (k == 0) {
        if (l == 0) { out[sample * 2] = 0.f; out[sample * 2 + 1] = 0.f; }
        return;
    }

    const float* Gfull = ws + 256;
    for (int a = 0; a < k; ++a) {
        const int ra = idx[a];
        for (int b = l; b < k; b += 64)
            Gm[a * (KMAX + 1) + b] = Gfull[ra * 256 + idx[b]];
    }
    for (int a = l; a < k; a += 64) {
        const int ma = idx[a];
        float acc = 0.f;
        #pragma unroll
        for (int i = 0; i < 64; ++i)
            acc += Dg[i * 256 + ma] * xv[i];
        rhs[a] = acc - LAMBD * sgn[a];
    }
    __syncthreads();

    // Cholesky (lower) in place, stride KMAX+1 kills bank conflicts
    for (int j = 0; j < k; ++j) {
        const float Ljj = sqrtf(fmaxf(Gm[j * (KMAX + 1) + j], 1e-30f));
        const float inv = 1.0f / Ljj;
        if (l == 0) Gm[j * (KMAX + 1) + j] = Ljj;
        for (int a = j + 1 + l; a < k; a += 64)
            Gm[a * (KMAX + 1) + j] *= inv;
        __syncthreads();
        for (int b = j + 1; b < k; ++b) {
            const float Lbj = Gm[b * (KMAX + 1) + j];
            for (int a = b + l; a < k; a += 64)
                Gm[a * (KMAX + 1) + b] -= Gm[a * (KMAX + 1) + j] * Lbj;
        }
        __syncthreads();
    }
    // forward: L y = rhs
    for (int j = 0; j < k; ++j) {
        const float yj = rhs[j] / Gm[j * (KMAX + 1) + j];
        if (l == 0) sol[j] = yj;
        for (int a = j + 1 + l; a < k; a += 64)
            rhs[a] -= Gm[a * (KMAX + 1) + j] * yj;
        __syncthreads();
    }
    // backward: L^T x = y
    for (int j = k - 1; j >= 0; --j) {
        const float xj = sol[j] / Gm[j * (KMAX + 1) + j];
        if (l == 0) sol[j] = xj;
        for (int a = l; a < j; a += 64)
            sol[a] -= Gm[j * (KMAX + 1) + a] * xj;
        __syncthreads();
    }
    float acc = 0.f;
    for (int a = l; a < k; a += 64)
        acc += wg[idx[a]] * sol[a];
    for (int d = 1; d < 64; d <<= 1) acc += __shfl_xor(acc, d);
    if (l == 0) { out[sample * 2] = acc; out[sample * 2 + 1] = -acc; }
}

extern "C" void kernel_launch(void* const* d_in, const int* in_sizes, int n_in,
                              void* d_out, int out_size, void* d_ws, size_t ws_size,
                              hipStream_t stream) {
    const float* x = (const float*)d_in[0];   // (1024, 64)
    const float* D = (const float*)d_in[1];   // (64, 256)
    const float* w = (const float*)d_in[2];   // (256,)
    float* out = (float*)d_out;               // (1024, 2)
    float* ws  = (float*)d_ws;
    float* Gfull = ws + 256;                  // 256*256
    float* zbuf  = ws + 256 + 65536;          // 1024*256

    eta_kernel<<<1, 256, 0, stream>>>(D, ws);
    gram_kernel<<<256, 256, 0, stream>>>(D, Gfull);
    ista_kernel<<<256, 256, 0, stream>>>(x, D, ws, zbuf);
    solve_kernel<<<1024, 64, 0, stream>>>(x, D, w, ws, zbuf, out);
}

// Round 3
// 1531.225 us; speedup vs baseline: 1.4654x; 1.3964x over previous
//
#include <hip/hip_runtime.h>

#define LAMBD 0.2f
#define KMAX 128

__device__ __forceinline__ float ssh(float v, float thr) {
    float a = fabsf(v) - thr;
    return a > 0.0f ? copysignf(a, v) : 0.0f;
}

__device__ __forceinline__ float rlane(float v, int lane) {
    return __int_as_float(__builtin_amdgcn_readlane(__float_as_int(v), lane));
}

// ---------------- Kernel 1: eta = 1 / sigma_max(D)^2 via power iteration on B = D D^T ----
__global__ __launch_bounds__(256) void eta_kernel(const float* __restrict__ Dg,
                                                  float* __restrict__ ws)
{
    __shared__ __align__(16) float Dc[256 * 68];  // Dc[m*68+i] = D[i][m], pad 68 for banks
    __shared__ __align__(16) float Bm[64 * 68];   // Bm[j*68+i] = B[j][i] (symmetric)
    __shared__ float vv[64];
    __shared__ float part[4 * 64];
    __shared__ float lamsh;

    const int t = threadIdx.x;
    for (int i = 0; i < 64; ++i)
        Dc[t * 68 + i] = Dg[i * 256 + t];          // coalesced global reads
    __syncthreads();

    // B = D D^T, 4x4 register tile per thread
    const int ti = t >> 4, tj = t & 15;
    float acc[4][4];
    #pragma unroll
    for (int r = 0; r < 4; ++r)
        #pragma unroll
        for (int c = 0; c < 4; ++c) acc[r][c] = 0.f;
    for (int mm = 0; mm < 256; ++mm) {
        const float4 A = *(const float4*)&Dc[mm * 68 + 4 * ti];
        const float4 Bv = *(const float4*)&Dc[mm * 68 + 4 * tj];
        const float Ae[4] = {A.x, A.y, A.z, A.w};
        const float Be[4] = {Bv.x, Bv.y, Bv.z, Bv.w};
        #pragma unroll
        for (int r = 0; r < 4; ++r)
            #pragma unroll
            for (int c = 0; c < 4; ++c)
                acc[r][c] += Ae[r] * Be[c];
    }
    #pragma unroll
    for (int r = 0; r < 4; ++r)
        #pragma unroll
        for (int c = 0; c < 4; ++c)
            Bm[(4 * ti + r) * 68 + (4 * tj + c)] = acc[r][c];
    if (t < 64) vv[t] = 0.125f;
    __syncthreads();

    for (int itp = 0; itp < 200; ++itp) {
        const int p = t >> 6, i = t & 63;
        float partial = 0.f;
        #pragma unroll
        for (int jj = 0; jj < 16; ++jj) {
            const int j = p * 16 + jj;
            partial += Bm[j * 68 + i] * vv[j];
        }
        part[p * 64 + i] = partial;
        __syncthreads();
        if (t < 64) {
            float nv = part[t] + part[64 + t] + part[128 + t] + part[192 + t];
            float n2 = nv * nv;
            for (int d = 1; d < 64; d <<= 1) n2 += __shfl_xor(n2, d);
            vv[t] = nv * rsqrtf(n2);
            if (t == 0) lamsh = n2;   // ||B v||^2 with v normalized -> lambda^2
        }
        __syncthreads();
    }
    if (t == 0) ws[0] = 1.0f / sqrtf(lamsh);   // eta = 1/lambda_max(B) = 1/sigma^2
}

// ---------------- Kernel 2: full Gram G = D^T D (256 x 256) ----------------
__global__ __launch_bounds__(256) void gram_kernel(const float* __restrict__ Dg,
                                                   float* __restrict__ Gfull)
{
    const int r = blockIdx.x, t = threadIdx.x;
    float acc = 0.f;
    #pragma unroll
    for (int i = 0; i < 64; ++i)
        acc += Dg[i * 256 + r] * Dg[i * 256 + t];
    Gfull[r * 256 + t] = acc;
}

// ---------------- Kernel 3: ISTA, 2 samples per workgroup, 512 blocks ----------------
// All D in VGPRs (pass-1 row tile + pass-2 column). z/res redistributed via
// v_readlane. 2 barriers/iter. Support-freeze early exit (256 stable iters).
__global__ __launch_bounds__(256, 2) void ista_kernel(const float* __restrict__ xg,
                                                      const float* __restrict__ Dg,
                                                      const float* __restrict__ ws,
                                                      float* __restrict__ zbuf)
{
    __shared__ float2 z2[256];        // z2[m] = z[m][s=0..1]
    __shared__ float2 part[4 * 64];   // per-wave partial res
    __shared__ float2 xs[64];         // x[i][s]
    __shared__ int    chgw[4];        // per-wave support-change flag

    const int t = threadIdx.x;
    const int w = t >> 6, l = t & 63;
    const int s0 = blockIdx.x * 2;

    // pass-1 D tile in registers: lane l of wave w holds D[l][64w .. 64w+63]
    float4 dreg[16];
    #pragma unroll
    for (int c = 0; c < 16; ++c)
        dreg[c] = *(const float4*)&Dg[l * 256 + 64 * w + 4 * c];

    // pass-2 D column in registers: thread t holds D[0..63][t]
    float dcol[64];
    #pragma unroll
    for (int i = 0; i < 64; ++i)
        dcol[i] = Dg[i * 256 + t];

    if (t < 64) {
        float2 v;
        v.x = xg[(s0 + 0) * 64 + t];
        v.y = xg[(s0 + 1) * 64 + t];
        xs[t] = v;
    }
    z2[t] = make_float2(0.f, 0.f);
    const float eta = ws[0];
    const float thr = LAMBD * eta;
    __syncthreads();

    float2 zown = make_float2(0.f, 0.f);   // thread t owns z[t] for both samples
    int stable = 0;
    for (int it = 0; it < 1001; ++it) {
        // ---- pass 1: part[w][l] = sum_{m in wave range} D[l][m] * z[m][s]
        const float2 zq = z2[64 * w + l];
        float2 acc = make_float2(0.f, 0.f);
        #pragma unroll
        for (int c = 0; c < 16; ++c) {
            const float4 d = dreg[c];
            const float de[4] = {d.x, d.y, d.z, d.w};
            #pragma unroll
            for (int j = 0; j < 4; ++j) {
                const int src = 4 * c + j;
                const float zx = rlane(zq.x, src);
                const float zy = rlane(zq.y, src);
                acc.x += de[j] * zx;
                acc.y += de[j] * zy;
            }
        }
        part[w * 64 + l] = acc;
        __syncthreads();

        // ---- pass 2 (fused reduce): res[l] computed per-lane, broadcast via readlane
        const float2 p0 = part[l], p1 = part[64 + l], p2 = part[128 + l], p3 = part[192 + l];
        const float2 xv = xs[l];
        float2 rq;
        rq.x = p0.x + p1.x + p2.x + p3.x - xv.x;
        rq.y = p0.y + p1.y + p2.y + p3.y - xv.y;
        float2 g = make_float2(0.f, 0.f);
        #pragma unroll
        for (int i = 0; i < 64; ++i) {
            const float rx = rlane(rq.x, i);
            const float ry = rlane(rq.y, i);
            g.x += dcol[i] * rx;
            g.y += dcol[i] * ry;
        }
        float2 zn;
        zn.x = ssh(zown.x - eta * g.x, thr);
        zn.y = ssh(zown.y - eta * g.y, thr);

        // support/sign change detection (block-uniform exit decision)
        const bool chg = ((zn.x > 0.f) != (zown.x > 0.f)) | ((zn.x < 0.f) != (zown.x < 0.f)) |
                         ((zn.y > 0.f) != (zown.y > 0.f)) | ((zn.y < 0.f) != (zown.y < 0.f));
        const bool anyw = __any(chg);
        z2[t] = zn;
        zown = zn;
        if (l == 0) chgw[w] = anyw ? 1 : 0;
        __syncthreads();   // covers z2 write -> next pass1 read, part reads -> next write, chgw

        const int anyblk = chgw[0] | chgw[1] | chgw[2] | chgw[3];
        stable = anyblk ? 0 : stable + 1;
        if (stable >= 256) break;
    }
    zbuf[(s0 + 0) * 256 + t] = zown.x;
    zbuf[(s0 + 1) * 256 + t] = zown.y;
}

// ---------------- Kernel 4: per-sample support solve (Cholesky) + y = w . alpha ----------
__global__ __launch_bounds__(64) void solve_kernel(const float* __restrict__ xg,
                                                   const float* __restrict__ Dg,
                                                   const float* __restrict__ wg,
                                                   const float* __restrict__ ws,
                                                   const float* __restrict__ zbuf,
                                                   float* __restrict__ out)
{
    __shared__ __align__(16) float Gm[KMAX * (KMAX + 1)];
    __shared__ int   idx[KMAX];
    __shared__ float sgn[KMAX];
    __shared__ float rhs[KMAX];
    __shared__ float sol[KMAX];
    __shared__ float xv[64];

    const int l = threadIdx.x;
    const int sample = blockIdx.x;

    const float4* zb4 = (const float4*)(zbuf + sample * 256);
    const float4 zz = zb4[l];
    const int c0 = zz.x != 0.f, c1 = zz.y != 0.f, c2 = zz.z != 0.f, c3 = zz.w != 0.f;
    const int cnt = c0 + c1 + c2 + c3;
    int scan = cnt;
    for (int d = 1; d < 64; d <<= 1) {
        const int v = __shfl_up(scan, d);
        if (l >= d) scan += v;
    }
    int o = scan - cnt;
    int k = __shfl(scan, 63);
    if (k > KMAX) k = KMAX;
    if (c0) { if (o < KMAX) { idx[o] = 4 * l + 0; sgn[o] = zz.x > 0.f ? 1.f : -1.f; } ++o; }
    if (c1) { if (o < KMAX) { idx[o] = 4 * l + 1; sgn[o] = zz.y > 0.f ? 1.f : -1.f; } ++o; }
    if (c2) { if (o < KMAX) { idx[o] = 4 * l + 2; sgn[o] = zz.z > 0.f ? 1.f : -1.f; } ++o; }
    if (c3) { if (o < KMAX) { idx[o] = 4 * l + 3; sgn[o] = zz.w > 0.f ? 1.f : -1.f; } ++o; }
    xv[l] = xg[sample * 64 + l];
    __syncthreads();

    if (k == 0) {
        if (l == 0) { out[sample * 2] = 0.f; out[sample * 2 + 1] = 0.f; }
        return;
    }

    const float* Gfull = ws + 256;
    for (int a = 0; a < k; ++a) {
        const int ra = idx[a];
        for (int b = l; b < k; b += 64)
            Gm[a * (KMAX + 1) + b] = Gfull[ra * 256 + idx[b]];
    }
    for (int a = l; a < k; a += 64) {
        const int ma = idx[a];
        float acc = 0.f;
        #pragma unroll
        for (int i = 0; i < 64; ++i)
            acc += Dg[i * 256 + ma] * xv[i];
        rhs[a] = acc - LAMBD * sgn[a];
    }
    __syncthreads();

    // Cholesky (lower) in place, stride KMAX+1 kills bank conflicts
    for (int j = 0; j < k; ++j) {
        const float Ljj = sqrtf(fmaxf(Gm[j * (KMAX + 1) + j], 1e-30f));
        const float inv = 1.0f / Ljj;
        if (l == 0) Gm[j * (KMAX + 1) + j] = Ljj;
        for (int a = j + 1 + l; a < k; a += 64)
            Gm[a * (KMAX + 1) + j] *= inv;
        __syncthreads();
        for (int b = j + 1; b < k; ++b) {
            const float Lbj = Gm[b * (KMAX + 1) + j];
            for (int a = b + l; a < k; a += 64)
                Gm[a * (KMAX + 1) + b] -= Gm[a * (KMAX + 1) + j] * Lbj;
        }
        __syncthreads();
    }
    // forward: L y = rhs
    for (int j = 0; j < k; ++j) {
        const float yj = rhs[j] / Gm[j * (KMAX + 1) + j];
        if (l == 0) sol[j] = yj;
        for (int a = j + 1 + l; a < k; a += 64)
            rhs[a] -= Gm[a * (KMAX + 1) + j] * yj;
        __syncthreads();
    }
    // backward: L^T x = y
    for (int j = k - 1; j >= 0; --j) {
        const float xj = sol[j] / Gm[j * (KMAX + 1) + j];
        if (l == 0) sol[j] = xj;
        for (int a = l; a < j; a += 64)
            sol[a] -= Gm[j * (KMAX + 1) + a] * xj;
        __syncthreads();
    }
    float acc = 0.f;
    for (int a = l; a < k; a += 64)
        acc += wg[idx[a]] * sol[a];
    for (int d = 1; d < 64; d <<= 1) acc += __shfl_xor(acc, d);
    if (l == 0) { out[sample * 2] = acc; out[sample * 2 + 1] = -acc; }
}

extern "C" void kernel_launch(void* const* d_in, const int* in_sizes, int n_in,
                              void* d_out, int out_size, void* d_ws, size_t ws_size,
                              hipStream_t stream) {
    const float* x = (const float*)d_in[0];   // (1024, 64)
    const float* D = (const float*)d_in[1];   // (64, 256)
    const float* w = (const float*)d_in[2];   // (256,)
    float* out = (float*)d_out;               // (1024, 2)
    float* ws  = (float*)d_ws;
    float* Gfull = ws + 256;                  // 256*256
    float* zbuf  = ws + 256 + 65536;          // 1024*256

    eta_kernel<<<1, 256, 0, stream>>>(D, ws);
    gram_kernel<<<256, 256, 0, stream>>>(D, Gfull);
    ista_kernel<<<512, 256, 0, stream>>>(x, D, ws, zbuf);
    solve_kernel<<<1024, 64, 0, stream>>>(x, D, w, ws, zbuf, out);
}

// Round 4
// 407.745 us; speedup vs baseline: 5.5030x; 3.7554x over previous
//
#include <hip/hip_runtime.h>

#define LAMBD 0.2f
#define KMAX 128

using half8 = __attribute__((ext_vector_type(8))) _Float16;
using f32x4 = __attribute__((ext_vector_type(4))) float;

__device__ __forceinline__ float sshrink(float v, float thr) {
    // softshrink(v) = v - clamp(v, -thr, thr)   (med3-friendly)
    float c = fminf(fmaxf(v, -thr), thr);
    return v - c;
}

__device__ __forceinline__ unsigned pack2(_Float16 a, _Float16 b) {
    unsigned short ua = __builtin_bit_cast(unsigned short, a);
    unsigned short ub = __builtin_bit_cast(unsigned short, b);
    return (unsigned)ua | ((unsigned)ub << 16);
}

// ---------------- Kernel 1: eta = 1 / sigma_max(D)^2 via power iteration on B = D D^T ----
__global__ __launch_bounds__(256) void eta_kernel(const float* __restrict__ Dg,
                                                  float* __restrict__ ws)
{
    __shared__ __align__(16) float Dc[256 * 68];
    __shared__ __align__(16) float Bm[64 * 68];
    __shared__ float vv[64];
    __shared__ float part[4 * 64];
    __shared__ float lamsh;

    const int t = threadIdx.x;
    for (int i = 0; i < 64; ++i)
        Dc[t * 68 + i] = Dg[i * 256 + t];
    __syncthreads();

    const int ti = t >> 4, tj = t & 15;
    float acc[4][4];
    #pragma unroll
    for (int r = 0; r < 4; ++r)
        #pragma unroll
        for (int c = 0; c < 4; ++c) acc[r][c] = 0.f;
    for (int mm = 0; mm < 256; ++mm) {
        const float4 A = *(const float4*)&Dc[mm * 68 + 4 * ti];
        const float4 Bv = *(const float4*)&Dc[mm * 68 + 4 * tj];
        const float Ae[4] = {A.x, A.y, A.z, A.w};
        const float Be[4] = {Bv.x, Bv.y, Bv.z, Bv.w};
        #pragma unroll
        for (int r = 0; r < 4; ++r)
            #pragma unroll
            for (int c = 0; c < 4; ++c)
                acc[r][c] += Ae[r] * Be[c];
    }
    #pragma unroll
    for (int r = 0; r < 4; ++r)
        #pragma unroll
        for (int c = 0; c < 4; ++c)
            Bm[(4 * ti + r) * 68 + (4 * tj + c)] = acc[r][c];
    if (t < 64) vv[t] = 0.125f;
    __syncthreads();

    for (int itp = 0; itp < 200; ++itp) {
        const int p = t >> 6, i = t & 63;
        float partial = 0.f;
        #pragma unroll
        for (int jj = 0; jj < 16; ++jj) {
            const int j = p * 16 + jj;
            partial += Bm[j * 68 + i] * vv[j];
        }
        part[p * 64 + i] = partial;
        __syncthreads();
        if (t < 64) {
            float nv = part[t] + part[64 + t] + part[128 + t] + part[192 + t];
            float n2 = nv * nv;
            for (int d = 1; d < 64; d <<= 1) n2 += __shfl_xor(n2, d);
            vv[t] = nv * rsqrtf(n2);
            if (t == 0) lamsh = n2;
        }
        __syncthreads();
    }
    if (t == 0) ws[0] = 1.0f / sqrtf(lamsh);
}

// ---------------- Kernel 2: full Gram G = D^T D (256 x 256) ----------------
__global__ __launch_bounds__(256) void gram_kernel(const float* __restrict__ Dg,
                                                   float* __restrict__ Gfull)
{
    const int r = blockIdx.x, t = threadIdx.x;
    float acc = 0.f;
    #pragma unroll
    for (int i = 0; i < 64; ++i)
        acc += Dg[i * 256 + r] * Dg[i * 256 + t];
    Gfull[r * 256 + t] = acc;
}

// ---------------- Kernel 2b: W = I - eta*G, split to f16 hi + lo*2048 ----------------
__global__ __launch_bounds__(256) void wbuild_kernel(const float* __restrict__ Gfull,
                                                     const float* __restrict__ ws,
                                                     _Float16* __restrict__ Whi,
                                                     _Float16* __restrict__ Wlo)
{
    const int r = blockIdx.x, c = threadIdx.x;
    const float eta = ws[0];
    const float wv = (r == c ? 1.0f : 0.0f) - eta * Gfull[r * 256 + c];
    const _Float16 wh = (_Float16)wv;
    const float rsd = (wv - (float)wh) * 2048.0f;
    Whi[r * 256 + c] = wh;
    Wlo[r * 256 + c] = (_Float16)rsd;
}

// ---------------- Kernel 2c: cbuf[s][r] = (D^T x_s)[r]  (no eta) ----------------
__global__ __launch_bounds__(256) void cbuf_kernel(const float* __restrict__ xg,
                                                   const float* __restrict__ Dg,
                                                   float* __restrict__ cbuf)
{
    __shared__ float xsh[4][64];
    const int t = threadIdx.x;
    const int s0 = blockIdx.x * 4;
    xsh[t >> 6][t & 63] = xg[s0 * 64 + t];
    __syncthreads();
    float a0 = 0.f, a1 = 0.f, a2 = 0.f, a3 = 0.f;
    #pragma unroll
    for (int i = 0; i < 64; ++i) {
        const float dv = Dg[i * 256 + t];
        a0 += xsh[0][i] * dv;
        a1 += xsh[1][i] * dv;
        a2 += xsh[2][i] * dv;
        a3 += xsh[3][i] * dv;
    }
    cbuf[(s0 + 0) * 256 + t] = a0;
    cbuf[(s0 + 1) * 256 + t] = a1;
    cbuf[(s0 + 2) * 256 + t] = a2;
    cbuf[(s0 + 3) * 256 + t] = a3;
}

// ---------------- Kernel 3: ISTA via MFMA on delta-z ----------------
// z <- ssh(W z + b); P = W z kept in persistent accumulators, P += W*dz per iter,
// dz rounded to f16 (z advanced by exactly the rounded step -> consistent).
// Block: 4 samples (cols 0..3 of N=16 tile), 4 waves x 64 rows of M=256.
__global__ __launch_bounds__(256, 1) void ista_kernel(const float* __restrict__ cbuf,
                                                      const _Float16* __restrict__ Whi,
                                                      const _Float16* __restrict__ Wlo,
                                                      const float* __restrict__ ws,
                                                      float* __restrict__ zbuf)
{
    __shared__ __align__(16) _Float16 dbuf[2][16][264];   // [buf][n][row-k], pad 264
    __shared__ int chgs[4];

    const int t = threadIdx.x;
    const int w = t >> 6, l = t & 63;
    const int n = l & 15, kg = l >> 4;
    const int s0 = blockIdx.x * 4;
    const float eta = ws[0];
    const float thr = LAMBD * eta;
    const float S = 1.0f / 2048.0f;
    const float FLUSH = 6.2e-5f;   // >= f16 min normal: avoids MFMA denorm inconsistency

    // --- W fragments (A-operand, 16x16x32): lane row = 64w+16a+(l&15), k = kt*32+kg*8+j
    const half8* Whi8 = (const half8*)Whi;
    const half8* Wlo8 = (const half8*)Wlo;
    half8 wh[4][8], wl[4][8];
    #pragma unroll
    for (int a = 0; a < 4; ++a) {
        const int row = 64 * w + 16 * a + n;
        #pragma unroll
        for (int kt = 0; kt < 8; ++kt) {
            wh[a][kt] = Whi8[row * 32 + kt * 4 + kg];
            wl[a][kt] = Wlo8[row * 32 + kt * 4 + kg];
        }
    }

    // --- b in C/D layout: row = 64w+16a+4kg+jj, col n
    float bv[4][4], z[4][4], znv[4][4];
    #pragma unroll
    for (int a = 0; a < 4; ++a)
        #pragma unroll
        for (int jj = 0; jj < 4; ++jj) {
            const int row = 64 * w + 16 * a + 4 * kg + jj;
            bv[a][jj] = (n < 4) ? eta * cbuf[(s0 + n) * 256 + row] : 0.f;
            z[a][jj] = 0.f;
        }

    f32x4 acc1[4], acc2[4];
    #pragma unroll
    for (int a = 0; a < 4; ++a) {
        acc1[a] = (f32x4){0.f, 0.f, 0.f, 0.f};
        acc2[a] = (f32x4){0.f, 0.f, 0.f, 0.f};
    }

    int cur = 0;
    for (int it = 0; ; ++it) {
        // ---- epilogue: zn = ssh(P + b); delta -> f16 (flushed); z += (f32)dh
        bool anyflag = false;
        _Float16 dh16[4][4];
        #pragma unroll
        for (int a = 0; a < 4; ++a)
            #pragma unroll
            for (int jj = 0; jj < 4; ++jj) {
                const float P = acc1[a][jj] + S * acc2[a][jj];
                const float zn = sshrink(P + bv[a][jj], thr);
                znv[a][jj] = zn;
                const float d = zn - z[a][jj];
                const bool live = fabsf(d) >= FLUSH;
                anyflag |= live;
                const _Float16 hd = live ? (_Float16)d : (_Float16)0.0f;
                dh16[a][jj] = hd;
                z[a][jj] += (float)hd;
            }
        if (it == 1000) break;

        const int anyw = __any(anyflag);
        if (l == 0) chgs[w] = anyw;
        // ---- write dz (f16) to LDS, rows 64w+16a+4kg+0..3, col n
        #pragma unroll
        for (int a = 0; a < 4; ++a) {
            const unsigned lo = pack2(dh16[a][0], dh16[a][1]);
            const unsigned hi = pack2(dh16[a][2], dh16[a][3]);
            *(uint2*)&dbuf[cur][n][64 * w + 16 * a + 4 * kg] = make_uint2(lo, hi);
        }
        __syncthreads();
        if (!(chgs[0] | chgs[1] | chgs[2] | chgs[3])) break;   // exact fixed point

        // ---- B fragments: lane col n, k = kt*32 + kg*8 + j
        half8 dh[8];
        #pragma unroll
        for (int kt = 0; kt < 8; ++kt)
            dh[kt] = *(const half8*)&dbuf[cur][n][kt * 32 + kg * 8];

        #pragma unroll
        for (int kt = 0; kt < 8; ++kt)
            #pragma unroll
            for (int a = 0; a < 4; ++a) {
                acc1[a] = __builtin_amdgcn_mfma_f32_16x16x32_f16(wh[a][kt], dh[kt], acc1[a], 0, 0, 0);
                acc2[a] = __builtin_amdgcn_mfma_f32_16x16x32_f16(wl[a][kt], dh[kt], acc2[a], 0, 0, 0);
            }
        cur ^= 1;
    }

    if (n < 4) {
        #pragma unroll
        for (int a = 0; a < 4; ++a)
            #pragma unroll
            for (int jj = 0; jj < 4; ++jj)
                zbuf[(s0 + n) * 256 + (64 * w + 16 * a + 4 * kg + jj)] = znv[a][jj];
    }
}

// ---------------- Kernel 4: per-sample support solve (Cholesky) + y = w . alpha ----------
__global__ __launch_bounds__(64) void solve_kernel(const float* __restrict__ xg,
                                                   const float* __restrict__ Dg,
                                                   const float* __restrict__ wg,
                                                   const float* __restrict__ ws,
                                                   const float* __restrict__ zbuf,
                                                   float* __restrict__ out)
{
    __shared__ __align__(16) float Gm[KMAX * (KMAX + 1)];
    __shared__ int   idx[KMAX];
    __shared__ float sgn[KMAX];
    __shared__ float rhs[KMAX];
    __shared__ float sol[KMAX];
    __shared__ float xv[64];

    const int l = threadIdx.x;
    const int sample = blockIdx.x;

    const float4* zb4 = (const float4*)(zbuf + sample * 256);
    const float4 zz = zb4[l];
    const int c0 = zz.x != 0.f, c1 = zz.y != 0.f, c2 = zz.z != 0.f, c3 = zz.w != 0.f;
    const int cnt = c0 + c1 + c2 + c3;
    int scan = cnt;
    for (int d = 1; d < 64; d <<= 1) {
        const int v = __shfl_up(scan, d);
        if (l >= d) scan += v;
    }
    int o = scan - cnt;
    int k = __shfl(scan, 63);
    if (k > KMAX) k = KMAX;
    if (c0) { if (o < KMAX) { idx[o] = 4 * l + 0; sgn[o] = zz.x > 0.f ? 1.f : -1.f; } ++o; }
    if (c1) { if (o < KMAX) { idx[o] = 4 * l + 1; sgn[o] = zz.y > 0.f ? 1.f : -1.f; } ++o; }
    if (c2) { if (o < KMAX) { idx[o] = 4 * l + 2; sgn[o] = zz.z > 0.f ? 1.f : -1.f; } ++o; }
    if (c3) { if (o < KMAX) { idx[o] = 4 * l + 3; sgn[o] = zz.w > 0.f ? 1.f : -1.f; } ++o; }
    xv[l] = xg[sample * 64 + l];
    __syncthreads();

    if (k == 0) {
        if (l == 0) { out[sample * 2] = 0.f; out[sample * 2 + 1] = 0.f; }
        return;
    }

    const float* Gfull = ws + 256;
    for (int a = 0; a < k; ++a) {
        const int ra = idx[a];
        for (int b = l; b < k; b += 64)
            Gm[a * (KMAX + 1) + b] = Gfull[ra * 256 + idx[b]];
    }
    for (int a = l; a < k; a += 64) {
        const int ma = idx[a];
        float acc = 0.f;
        #pragma unroll
        for (int i = 0; i < 64; ++i)
            acc += Dg[i * 256 + ma] * xv[i];
        rhs[a] = acc - LAMBD * sgn[a];
    }
    __syncthreads();

    for (int j = 0; j < k; ++j) {
        const float Ljj = sqrtf(fmaxf(Gm[j * (KMAX + 1) + j], 1e-30f));
        const float inv = 1.0f / Ljj;
        if (l == 0) Gm[j * (KMAX + 1) + j] = Ljj;
        for (int a = j + 1 + l; a < k; a += 64)
            Gm[a * (KMAX + 1) + j] *= inv;
        __syncthreads();
        for (int b = j + 1; b < k; ++b) {
            const float Lbj = Gm[b * (KMAX + 1) + j];
            for (int a = b + l; a < k; a += 64)
                Gm[a * (KMAX + 1) + b] -= Gm[a * (KMAX + 1) + j] * Lbj;
        }
        __syncthreads();
    }
    for (int j = 0; j < k; ++j) {
        const float yj = rhs[j] / Gm[j * (KMAX + 1) + j];
        if (l == 0) sol[j] = yj;
        for (int a = j + 1 + l; a < k; a += 64)
            rhs[a] -= Gm[a * (KMAX + 1) + j] * yj;
        __syncthreads();
    }
    for (int j = k - 1; j >= 0; --j) {
        const float xj = sol[j] / Gm[j * (KMAX + 1) + j];
        if (l == 0) sol[j] = xj;
        for (int a = l; a < j; a += 64)
            sol[a] -= Gm[j * (KMAX + 1) + a] * xj;
        __syncthreads();
    }
    float acc = 0.f;
    for (int a = l; a < k; a += 64)
        acc += wg[idx[a]] * sol[a];
    for (int d = 1; d < 64; d <<= 1) acc += __shfl_xor(acc, d);
    if (l == 0) { out[sample * 2] = acc; out[sample * 2 + 1] = -acc; }
}

extern "C" void kernel_launch(void* const* d_in, const int* in_sizes, int n_in,
                              void* d_out, int out_size, void* d_ws, size_t ws_size,
                              hipStream_t stream) {
    const float* x = (const float*)d_in[0];   // (1024, 64)
    const float* D = (const float*)d_in[1];   // (64, 256)
    const float* w = (const float*)d_in[2];   // (256,)
    float* out = (float*)d_out;               // (1024, 2)
    float* ws  = (float*)d_ws;

    float* Gfull = ws + 256;                        // 65536 floats
    float* zbuf  = ws + 256 + 65536;                // 262144 floats
    float* cbuf  = ws + 256 + 65536 + 262144;       // 262144 floats
    _Float16* Whalf = (_Float16*)(ws + 256 + 65536 + 262144 + 262144);
    _Float16* Whi = Whalf;                          // 65536 halves
    _Float16* Wlo = Whalf + 65536;                  // 65536 halves

    eta_kernel<<<1, 256, 0, stream>>>(D, ws);
    gram_kernel<<<256, 256, 0, stream>>>(D, Gfull);
    wbuild_kernel<<<256, 256, 0, stream>>>(Gfull, ws, Whi, Wlo);
    cbuf_kernel<<<256, 256, 0, stream>>>(x, D, cbuf);
    ista_kernel<<<256, 256, 0, stream>>>(cbuf, Whi, Wlo, ws, zbuf);
    solve_kernel<<<1024, 64, 0, stream>>>(x, D, w, ws, zbuf, out);
}

// Round 5
// 305.583 us; speedup vs baseline: 7.3428x; 1.3343x over previous
//
#include <hip/hip_runtime.h>

#define LAMBD 0.2f
#define KMAX 128
#define KS 64

using half8 = __attribute__((ext_vector_type(8))) _Float16;
using f32x4 = __attribute__((ext_vector_type(4))) float;

__device__ __forceinline__ float sshrink(float v, float thr) {
    float c = fminf(fmaxf(v, -thr), thr);
    return v - c;
}

__device__ __forceinline__ unsigned pack2(_Float16 a, _Float16 b) {
    unsigned short ua = __builtin_bit_cast(unsigned short, a);
    unsigned short ub = __builtin_bit_cast(unsigned short, b);
    return (unsigned)ua | ((unsigned)ub << 16);
}

// ---------------- Kernel 1: eta = 1 / sigma_max(D)^2 via power iteration on B = D D^T ----
__global__ __launch_bounds__(256) void eta_kernel(const float* __restrict__ Dg,
                                                  float* __restrict__ ws)
{
    __shared__ __align__(16) float Dc[256 * 68];
    __shared__ __align__(16) float Bm[64 * 68];
    __shared__ float vv[64];
    __shared__ float part[4 * 64];
    __shared__ float lamsh;

    const int t = threadIdx.x;
    for (int i = 0; i < 64; ++i)
        Dc[t * 68 + i] = Dg[i * 256 + t];
    __syncthreads();

    const int ti = t >> 4, tj = t & 15;
    float acc[4][4];
    #pragma unroll
    for (int r = 0; r < 4; ++r)
        #pragma unroll
        for (int c = 0; c < 4; ++c) acc[r][c] = 0.f;
    for (int mm = 0; mm < 256; ++mm) {
        const float4 A = *(const float4*)&Dc[mm * 68 + 4 * ti];
        const float4 Bv = *(const float4*)&Dc[mm * 68 + 4 * tj];
        const float Ae[4] = {A.x, A.y, A.z, A.w};
        const float Be[4] = {Bv.x, Bv.y, Bv.z, Bv.w};
        #pragma unroll
        for (int r = 0; r < 4; ++r)
            #pragma unroll
            for (int c = 0; c < 4; ++c)
                acc[r][c] += Ae[r] * Be[c];
    }
    #pragma unroll
    for (int r = 0; r < 4; ++r)
        #pragma unroll
        for (int c = 0; c < 4; ++c)
            Bm[(4 * ti + r) * 68 + (4 * tj + c)] = acc[r][c];
    if (t < 64) vv[t] = 0.125f;
    __syncthreads();

    for (int itp = 0; itp < 64; ++itp) {
        const int p = t >> 6, i = t & 63;
        float partial = 0.f;
        #pragma unroll
        for (int jj = 0; jj < 16; ++jj) {
            const int j = p * 16 + jj;
            partial += Bm[j * 68 + i] * vv[j];
        }
        part[p * 64 + i] = partial;
        __syncthreads();
        if (t < 64) {
            float nv = part[t] + part[64 + t] + part[128 + t] + part[192 + t];
            float n2 = nv * nv;
            for (int d = 1; d < 64; d <<= 1) n2 += __shfl_xor(n2, d);
            vv[t] = nv * rsqrtf(n2);
            if (t == 0) lamsh = n2;
        }
        __syncthreads();
    }
    if (t == 0) ws[0] = 1.0f / sqrtf(lamsh);
}

// ---------------- Kernel 2 (fused prep): G row, W=I-etaG split f16, cbuf = D^T x ----------
__global__ __launch_bounds__(256) void prep_kernel(const float* __restrict__ xg,
                                                   const float* __restrict__ Dg,
                                                   const float* __restrict__ ws,
                                                   float* __restrict__ Gfull,
                                                   _Float16* __restrict__ Whi,
                                                   _Float16* __restrict__ Wlo,
                                                   float* __restrict__ cbuf)
{
    __shared__ float xsh[4][64];
    const int t = threadIdx.x;
    const int r = blockIdx.x;
    const int s0 = r * 4;
    xsh[t >> 6][t & 63] = xg[s0 * 64 + t];
    __syncthreads();

    float accG = 0.f, a0 = 0.f, a1 = 0.f, a2 = 0.f, a3 = 0.f;
    #pragma unroll
    for (int i = 0; i < 64; ++i) {
        const float dv = Dg[i * 256 + t];
        const float dr = Dg[i * 256 + r];
        accG += dr * dv;
        a0 += xsh[0][i] * dv;
        a1 += xsh[1][i] * dv;
        a2 += xsh[2][i] * dv;
        a3 += xsh[3][i] * dv;
    }
    Gfull[r * 256 + t] = accG;
    const float eta = ws[0];
    const float wv = (r == t ? 1.0f : 0.0f) - eta * accG;
    const _Float16 wh = (_Float16)wv;
    Whi[r * 256 + t] = wh;
    Wlo[r * 256 + t] = (_Float16)((wv - (float)wh) * 2048.0f);
    cbuf[(s0 + 0) * 256 + t] = a0;
    cbuf[(s0 + 1) * 256 + t] = a1;
    cbuf[(s0 + 2) * 256 + t] = a2;
    cbuf[(s0 + 3) * 256 + t] = a3;
}

// ---------------- Kernel 3: ISTA via MFMA on delta-z (unchanged from R4) ----------------
__global__ __launch_bounds__(256, 1) void ista_kernel(const float* __restrict__ cbuf,
                                                      const _Float16* __restrict__ Whi,
                                                      const _Float16* __restrict__ Wlo,
                                                      const float* __restrict__ ws,
                                                      float* __restrict__ zbuf)
{
    __shared__ __align__(16) _Float16 dbuf[2][16][264];
    __shared__ int chgs[4];

    const int t = threadIdx.x;
    const int w = t >> 6, l = t & 63;
    const int n = l & 15, kg = l >> 4;
    const int s0 = blockIdx.x * 4;
    const float eta = ws[0];
    const float thr = LAMBD * eta;
    const float S = 1.0f / 2048.0f;
    const float FLUSH = 6.2e-5f;

    const half8* Whi8 = (const half8*)Whi;
    const half8* Wlo8 = (const half8*)Wlo;
    half8 wh[4][8], wl[4][8];
    #pragma unroll
    for (int a = 0; a < 4; ++a) {
        const int row = 64 * w + 16 * a + n;
        #pragma unroll
        for (int kt = 0; kt < 8; ++kt) {
            wh[a][kt] = Whi8[row * 32 + kt * 4 + kg];
            wl[a][kt] = Wlo8[row * 32 + kt * 4 + kg];
        }
    }

    float bv[4][4], z[4][4], znv[4][4];
    #pragma unroll
    for (int a = 0; a < 4; ++a)
        #pragma unroll
        for (int jj = 0; jj < 4; ++jj) {
            const int row = 64 * w + 16 * a + 4 * kg + jj;
            bv[a][jj] = (n < 4) ? eta * cbuf[(s0 + n) * 256 + row] : 0.f;
            z[a][jj] = 0.f;
        }

    f32x4 acc1[4], acc2[4];
    #pragma unroll
    for (int a = 0; a < 4; ++a) {
        acc1[a] = (f32x4){0.f, 0.f, 0.f, 0.f};
        acc2[a] = (f32x4){0.f, 0.f, 0.f, 0.f};
    }

    int cur = 0;
    for (int it = 0; ; ++it) {
        bool anyflag = false;
        _Float16 dh16[4][4];
        #pragma unroll
        for (int a = 0; a < 4; ++a)
            #pragma unroll
            for (int jj = 0; jj < 4; ++jj) {
                const float P = acc1[a][jj] + S * acc2[a][jj];
                const float zn = sshrink(P + bv[a][jj], thr);
                znv[a][jj] = zn;
                const float d = zn - z[a][jj];
                const bool live = fabsf(d) >= FLUSH;
                anyflag |= live;
                const _Float16 hd = live ? (_Float16)d : (_Float16)0.0f;
                dh16[a][jj] = hd;
                z[a][jj] += (float)hd;
            }
        if (it == 1000) break;

        const int anyw = __any(anyflag);
        if (l == 0) chgs[w] = anyw;
        #pragma unroll
        for (int a = 0; a < 4; ++a) {
            const unsigned lo = pack2(dh16[a][0], dh16[a][1]);
            const unsigned hi = pack2(dh16[a][2], dh16[a][3]);
            *(uint2*)&dbuf[cur][n][64 * w + 16 * a + 4 * kg] = make_uint2(lo, hi);
        }
        __syncthreads();
        if (!(chgs[0] | chgs[1] | chgs[2] | chgs[3])) break;

        half8 dh[8];
        #pragma unroll
        for (int kt = 0; kt < 8; ++kt)
            dh[kt] = *(const half8*)&dbuf[cur][n][kt * 32 + kg * 8];

        #pragma unroll
        for (int kt = 0; kt < 8; ++kt)
            #pragma unroll
            for (int a = 0; a < 4; ++a) {
                acc1[a] = __builtin_amdgcn_mfma_f32_16x16x32_f16(wh[a][kt], dh[kt], acc1[a], 0, 0, 0);
                acc2[a] = __builtin_amdgcn_mfma_f32_16x16x32_f16(wl[a][kt], dh[kt], acc2[a], 0, 0, 0);
            }
        cur ^= 1;
    }

    if (n < 4) {
        #pragma unroll
        for (int a = 0; a < 4; ++a)
            #pragma unroll
            for (int jj = 0; jj < 4; ++jj)
                zbuf[(s0 + n) * 256 + (64 * w + 16 * a + 4 * kg + jj)] = znv[a][jj];
    }
}

// ---------------- Kernel 4a: support solve, k <= 64 fast path ----------------
// 1 wave; Gm[64][65] = 16.6 KB -> 4+ blocks/CU resident. Lane-parallel Cholesky,
// shuffle-based fwd/bwd substitution (no LDS dependency chains).
__global__ __launch_bounds__(64) void solve_small(const float* __restrict__ Gfull,
                                                  const float* __restrict__ cbuf,
                                                  const float* __restrict__ wg,
                                                  const float* __restrict__ zbuf,
                                                  float* __restrict__ out)
{
    __shared__ __align__(16) float Gm[KS * (KS + 1)];
    __shared__ int   idxs[KS];
    __shared__ float sgns[KS];

    const int l = threadIdx.x;
    const int sample = blockIdx.x;

    const float4 zz = ((const float4*)(zbuf + sample * 256))[l];
    const int c0 = zz.x != 0.f, c1 = zz.y != 0.f, c2 = zz.z != 0.f, c3 = zz.w != 0.f;
    const int cnt = c0 + c1 + c2 + c3;
    int scan = cnt;
    for (int d = 1; d < 64; d <<= 1) {
        const int v = __shfl_up(scan, d);
        if (l >= d) scan += v;
    }
    int o = scan - cnt;
    const int k = __shfl(scan, 63);
    if (k > KS) return;                 // big-k fallback kernel handles
    if (k == 0) {
        if (l == 0) { out[sample * 2] = 0.f; out[sample * 2 + 1] = 0.f; }
        return;
    }
    if (c0) { idxs[o] = 4 * l + 0; sgns[o] = zz.x > 0.f ? 1.f : -1.f; ++o; }
    if (c1) { idxs[o] = 4 * l + 1; sgns[o] = zz.y > 0.f ? 1.f : -1.f; ++o; }
    if (c2) { idxs[o] = 4 * l + 2; sgns[o] = zz.z > 0.f ? 1.f : -1.f; ++o; }
    if (c3) { idxs[o] = 4 * l + 3; sgns[o] = zz.w > 0.f ? 1.f : -1.f; ++o; }
    __syncthreads();

    const int   ib = idxs[(l < k) ? l : (k - 1)];
    const float sg = (l < k) ? sgns[l] : 0.f;
    float rhs = (l < k) ? (cbuf[sample * 256 + ib] - LAMBD * sg) : 0.f;

    // gather G submatrix: row a, cols idx[0..k)
    for (int a = 0; a < k; ++a) {
        const int ra = __shfl(ib, a);
        if (l < k) Gm[a * (KS + 1) + l] = Gfull[ra * 256 + ib];
    }
    __syncthreads();

    // Cholesky, lane-parallel columns
    float dinv = 0.f;
    for (int j = 0; j < k; ++j) {
        const float Gjj = Gm[j * (KS + 1) + j];
        const float Ljj = sqrtf(fmaxf(Gjj, 1e-30f));
        const float iv = 1.0f / Ljj;
        float Laj = 0.f;
        if (l == j) { Gm[j * (KS + 1) + j] = Ljj; dinv = iv; }
        if (l > j && l < k) { Laj = Gm[l * (KS + 1) + j] * iv; Gm[l * (KS + 1) + j] = Laj; }
        __syncthreads();
        for (int b = j + 1; b < k; ++b) {
            const float Lbj = Gm[b * (KS + 1) + j];
            if (l >= b && l < k) Gm[l * (KS + 1) + b] -= Laj * Lbj;
        }
        __syncthreads();
    }

    // forward: L y = rhs (y in register, lane l owns index l)
    float y = rhs;
    for (int j = 0; j < k; ++j) {
        const float Laj = Gm[l * (KS + 1) + j];      // prefetchable, read-only now
        const float yjf = __shfl(y, j) * __shfl(dinv, j);
        if (l == j) y = yjf;
        if (l > j) y -= Laj * yjf;
    }
    // backward: L^T x = y
    float xv = y;
    for (int j = k - 1; j >= 0; --j) {
        const float Lja = Gm[j * (KS + 1) + l];
        const float xjf = __shfl(xv, j) * __shfl(dinv, j);
        if (l == j) xv = xjf;
        if (l < j) xv -= Lja * xjf;
    }

    float acc = (l < k) ? wg[ib] * xv : 0.f;
    for (int d = 1; d < 64; d <<= 1) acc += __shfl_xor(acc, d);
    if (l == 0) { out[sample * 2] = acc; out[sample * 2 + 1] = -acc; }
}

// ---------------- Kernel 4b: support solve, k > 64 fallback (rare/never) ----------------
__global__ __launch_bounds__(64) void solve_big(const float* __restrict__ Gfull,
                                                const float* __restrict__ cbuf,
                                                const float* __restrict__ wg,
                                                const float* __restrict__ zbuf,
                                                float* __restrict__ out)
{
    __shared__ __align__(16) float Gm[KMAX * (KMAX + 1)];
    __shared__ int   idx[KMAX];
    __shared__ float sgn[KMAX];
    __shared__ float rhs[KMAX];
    __shared__ float sol[KMAX];

    const int l = threadIdx.x;
    const int sample = blockIdx.x;

    const float4 zz = ((const float4*)(zbuf + sample * 256))[l];
    const int c0 = zz.x != 0.f, c1 = zz.y != 0.f, c2 = zz.z != 0.f, c3 = zz.w != 0.f;
    const int cnt = c0 + c1 + c2 + c3;
    int scan = cnt;
    for (int d = 1; d < 64; d <<= 1) {
        const int v = __shfl_up(scan, d);
        if (l >= d) scan += v;
    }
    int o = scan - cnt;
    int k = __shfl(scan, 63);
    if (k <= KS) return;                // small kernel handled it
    if (k > KMAX) k = KMAX;
    if (c0) { if (o < KMAX) { idx[o] = 4 * l + 0; sgn[o] = zz.x > 0.f ? 1.f : -1.f; } ++o; }
    if (c1) { if (o < KMAX) { idx[o] = 4 * l + 1; sgn[o] = zz.y > 0.f ? 1.f : -1.f; } ++o; }
    if (c2) { if (o < KMAX) { idx[o] = 4 * l + 2; sgn[o] = zz.z > 0.f ? 1.f : -1.f; } ++o; }
    if (c3) { if (o < KMAX) { idx[o] = 4 * l + 3; sgn[o] = zz.w > 0.f ? 1.f : -1.f; } ++o; }
    __syncthreads();

    for (int a = 0; a < k; ++a) {
        const int ra = idx[a];
        for (int b = l; b < k; b += 64)
            Gm[a * (KMAX + 1) + b] = Gfull[ra * 256 + idx[b]];
    }
    for (int a = l; a < k; a += 64)
        rhs[a] = cbuf[sample * 256 + idx[a]] - LAMBD * sgn[a];
    __syncthreads();

    for (int j = 0; j < k; ++j) {
        const float Ljj = sqrtf(fmaxf(Gm[j * (KMAX + 1) + j], 1e-30f));
        const float inv = 1.0f / Ljj;
        if (l == 0) Gm[j * (KMAX + 1) + j] = Ljj;
        for (int a = j + 1 + l; a < k; a += 64)
            Gm[a * (KMAX + 1) + j] *= inv;
        __syncthreads();
        for (int b = j + 1; b < k; ++b) {
            const float Lbj = Gm[b * (KMAX + 1) + j];
            for (int a = b + l; a < k; a += 64)
                Gm[a * (KMAX + 1) + b] -= Gm[a * (KMAX + 1) + j] * Lbj;
        }
        __syncthreads();
    }
    for (int j = 0; j < k; ++j) {
        const float yj = rhs[j] / Gm[j * (KMAX + 1) + j];
        if (l == 0) sol[j] = yj;
        for (int a = j + 1 + l; a < k; a += 64)
            rhs[a] -= Gm[a * (KMAX + 1) + j] * yj;
        __syncthreads();
    }
    for (int j = k - 1; j >= 0; --j) {
        const float xj = sol[j] / Gm[j * (KMAX + 1) + j];
        if (l == 0) sol[j] = xj;
        for (int a = l; a < j; a += 64)
            sol[a] -= Gm[j * (KMAX + 1) + a] * xj;
        __syncthreads();
    }
    float acc = 0.f;
    for (int a = l; a < k; a += 64)
        acc += wg[idx[a]] * sol[a];
    for (int d = 1; d < 64; d <<= 1) acc += __shfl_xor(acc, d);
    if (l == 0) { out[sample * 2] = acc; out[sample * 2 + 1] = -acc; }
}

extern "C" void kernel_launch(void* const* d_in, const int* in_sizes, int n_in,
                              void* d_out, int out_size, void* d_ws, size_t ws_size,
                              hipStream_t stream) {
    const float* x = (const float*)d_in[0];   // (1024, 64)
    const float* D = (const float*)d_in[1];   // (64, 256)
    const float* w = (const float*)d_in[2];   // (256,)
    float* out = (float*)d_out;               // (1024, 2)
    float* ws  = (float*)d_ws;

    float* Gfull = ws + 256;                        // 65536 floats
    float* zbuf  = ws + 256 + 65536;                // 262144 floats
    float* cbuf  = ws + 256 + 65536 + 262144;       // 262144 floats
    _Float16* Whalf = (_Float16*)(ws + 256 + 65536 + 262144 + 262144);
    _Float16* Whi = Whalf;                          // 65536 halves
    _Float16* Wlo = Whalf + 65536;                  // 65536 halves

    eta_kernel<<<1, 256, 0, stream>>>(D, ws);
    prep_kernel<<<256, 256, 0, stream>>>(x, D, ws, Gfull, Whi, Wlo, cbuf);
    ista_kernel<<<256, 256, 0, stream>>>(cbuf, Whi, Wlo, ws, zbuf);
    solve_small<<<1024, 64, 0, stream>>>(Gfull, cbuf, w, zbuf, out);
    solve_big<<<1024, 64, 0, stream>>>(Gfull, cbuf, w, zbuf, out);
}

// Round 6
// 243.698 us; speedup vs baseline: 9.2075x; 1.2539x over previous
//
#include <hip/hip_runtime.h>

#define LAMBD 0.2f
#define KMAX 128
#define KS 64
#define OS 1.9f    // overstep: any s < 2/L converges to the same lasso minimizer

using half8 = __attribute__((ext_vector_type(8))) _Float16;
using f32x4 = __attribute__((ext_vector_type(4))) float;

__device__ __forceinline__ float sshrink(float v, float thr) {
    float c = fminf(fmaxf(v, -thr), thr);
    return v - c;
}

__device__ __forceinline__ unsigned pack2(_Float16 a, _Float16 b) {
    unsigned short ua = __builtin_bit_cast(unsigned short, a);
    unsigned short ub = __builtin_bit_cast(unsigned short, b);
    return (unsigned)ua | ((unsigned)ub << 16);
}

// ---------------- Kernel 1: fused prep. Block 0: s = OS/sigma_max(D)^2 (power iter).
// Blocks 1..256: Gram row r + cbuf = D^T x. (G/cbuf don't need s; ista reads s.)
__global__ __launch_bounds__(256) void prep_all(const float* __restrict__ xg,
                                                const float* __restrict__ Dg,
                                                float* __restrict__ ws,
                                                float* __restrict__ Gfull,
                                                float* __restrict__ cbuf)
{
    const int t = threadIdx.x;
    if (blockIdx.x == 0) {
        __shared__ __align__(16) float Dc[256 * 68];
        __shared__ __align__(16) float Bm[64 * 68];
        __shared__ float vv[64];
        __shared__ float part[4 * 64];
        __shared__ float lamsh;

        for (int i = 0; i < 64; ++i)
            Dc[t * 68 + i] = Dg[i * 256 + t];
        __syncthreads();

        const int ti = t >> 4, tj = t & 15;
        float acc[4][4];
        #pragma unroll
        for (int r = 0; r < 4; ++r)
            #pragma unroll
            for (int c = 0; c < 4; ++c) acc[r][c] = 0.f;
        for (int mm = 0; mm < 256; ++mm) {
            const float4 A = *(const float4*)&Dc[mm * 68 + 4 * ti];
            const float4 Bv = *(const float4*)&Dc[mm * 68 + 4 * tj];
            const float Ae[4] = {A.x, A.y, A.z, A.w};
            const float Be[4] = {Bv.x, Bv.y, Bv.z, Bv.w};
            #pragma unroll
            for (int r = 0; r < 4; ++r)
                #pragma unroll
                for (int c = 0; c < 4; ++c)
                    acc[r][c] += Ae[r] * Be[c];
        }
        #pragma unroll
        for (int r = 0; r < 4; ++r)
            #pragma unroll
            for (int c = 0; c < 4; ++c)
                Bm[(4 * ti + r) * 68 + (4 * tj + c)] = acc[r][c];
        if (t < 64) vv[t] = 0.125f;
        __syncthreads();

        for (int itp = 0; itp < 64; ++itp) {
            const int p = t >> 6, i = t & 63;
            float partial = 0.f;
            #pragma unroll
            for (int jj = 0; jj < 16; ++jj) {
                const int j = p * 16 + jj;
                partial += Bm[j * 68 + i] * vv[j];
            }
            part[p * 64 + i] = partial;
            __syncthreads();
            if (t < 64) {
                float nv = part[t] + part[64 + t] + part[128 + t] + part[192 + t];
                float n2 = nv * nv;
                for (int d = 1; d < 64; d <<= 1) n2 += __shfl_xor(n2, d);
                vv[t] = nv * rsqrtf(n2);
                if (t == 0) lamsh = n2;
            }
            __syncthreads();
        }
        if (t == 0) ws[0] = OS / sqrtf(lamsh);   // s = OS/lambda_max(B)
    } else {
        __shared__ float xsh[4][64];
        const int r = blockIdx.x - 1;
        const int s0 = r * 4;
        xsh[t >> 6][t & 63] = xg[s0 * 64 + t];
        __syncthreads();

        float accG = 0.f, a0 = 0.f, a1 = 0.f, a2 = 0.f, a3 = 0.f;
        #pragma unroll
        for (int i = 0; i < 64; ++i) {
            const float dv = Dg[i * 256 + t];
            const float dr = Dg[i * 256 + r];
            accG += dr * dv;
            a0 += xsh[0][i] * dv;
            a1 += xsh[1][i] * dv;
            a2 += xsh[2][i] * dv;
            a3 += xsh[3][i] * dv;
        }
        Gfull[r * 256 + t] = accG;
        cbuf[(s0 + 0) * 256 + t] = a0;
        cbuf[(s0 + 1) * 256 + t] = a1;
        cbuf[(s0 + 2) * 256 + t] = a2;
        cbuf[(s0 + 3) * 256 + t] = a3;
    }
}

// ---------------- Kernel 2: ISTA (MFMA delta-z) + per-wave support solve ----------------
__global__ __launch_bounds__(256, 1) void ista_solve(const float* __restrict__ cbuf,
                                                     const float* __restrict__ Gfull,
                                                     const float* __restrict__ ws,
                                                     const float* __restrict__ wg,
                                                     float* __restrict__ zbuf,
                                                     int* __restrict__ kflag,
                                                     float* __restrict__ out)
{
    __shared__ __align__(16) _Float16 dbuf[2][16][264];
    __shared__ int chgs[4];
    __shared__ __align__(16) float znb[4][264];          // [sample][row]
    __shared__ __align__(16) float Gm[4][KS * (KS + 1)]; // per-wave Cholesky
    __shared__ int   idxs[4][KS];
    __shared__ float sgns[4][KS];

    const int t = threadIdx.x;
    const int w = t >> 6, l = t & 63;
    const int n = l & 15, kg = l >> 4;
    const int s0 = blockIdx.x * 4;
    const float s = ws[0];
    const float thr = LAMBD * s;
    const float S = 1.0f / 2048.0f;
    const float FLUSH = 6.2e-5f;

    // --- build W = I - s*G fragments directly from Gfull (fp32 -> f16 hi/lo)
    half8 wh[4][8], wl[4][8];
    #pragma unroll
    for (int a = 0; a < 4; ++a) {
        const int row = 64 * w + 16 * a + n;
        #pragma unroll
        for (int kt = 0; kt < 8; ++kt) {
            const float4 g0 = *(const float4*)&Gfull[row * 256 + kt * 32 + kg * 8];
            const float4 g1 = *(const float4*)&Gfull[row * 256 + kt * 32 + kg * 8 + 4];
            const float ge[8] = {g0.x, g0.y, g0.z, g0.w, g1.x, g1.y, g1.z, g1.w};
            half8 h, lo;
            #pragma unroll
            for (int j = 0; j < 8; ++j) {
                const int col = kt * 32 + kg * 8 + j;
                const float wv = (row == col ? 1.0f : 0.0f) - s * ge[j];
                const _Float16 whj = (_Float16)wv;
                h[j] = whj;
                lo[j] = (_Float16)((wv - (float)whj) * 2048.0f);
            }
            wh[a][kt] = h;
            wl[a][kt] = lo;
        }
    }

    float bv[4][4], z[4][4], znv[4][4];
    #pragma unroll
    for (int a = 0; a < 4; ++a)
        #pragma unroll
        for (int jj = 0; jj < 4; ++jj) {
            const int row = 64 * w + 16 * a + 4 * kg + jj;
            bv[a][jj] = (n < 4) ? s * cbuf[(s0 + n) * 256 + row] : 0.f;
            z[a][jj] = 0.f;
        }

    f32x4 acc1[4], acc2[4];
    #pragma unroll
    for (int a = 0; a < 4; ++a) {
        acc1[a] = (f32x4){0.f, 0.f, 0.f, 0.f};
        acc2[a] = (f32x4){0.f, 0.f, 0.f, 0.f};
    }

    int cur = 0;
    for (int it = 0; ; ++it) {
        bool anyflag = false;
        _Float16 dh16[4][4];
        #pragma unroll
        for (int a = 0; a < 4; ++a)
            #pragma unroll
            for (int jj = 0; jj < 4; ++jj) {
                const float P = acc1[a][jj] + S * acc2[a][jj];
                const float zn = sshrink(P + bv[a][jj], thr);
                znv[a][jj] = zn;
                const float d = zn - z[a][jj];
                const bool live = fabsf(d) >= FLUSH;
                anyflag |= live;
                const _Float16 hd = live ? (_Float16)d : (_Float16)0.0f;
                dh16[a][jj] = hd;
                z[a][jj] += (float)hd;
            }
        if (it == 1000) break;

        const int anyw = __any(anyflag);
        if (l == 0) chgs[w] = anyw;
        #pragma unroll
        for (int a = 0; a < 4; ++a) {
            const unsigned lo = pack2(dh16[a][0], dh16[a][1]);
            const unsigned hi = pack2(dh16[a][2], dh16[a][3]);
            *(uint2*)&dbuf[cur][n][64 * w + 16 * a + 4 * kg] = make_uint2(lo, hi);
        }
        __syncthreads();
        if (!(chgs[0] | chgs[1] | chgs[2] | chgs[3])) break;

        half8 dh[8];
        #pragma unroll
        for (int kt = 0; kt < 8; ++kt)
            dh[kt] = *(const half8*)&dbuf[cur][n][kt * 32 + kg * 8];

        #pragma unroll
        for (int kt = 0; kt < 8; ++kt)
            #pragma unroll
            for (int a = 0; a < 4; ++a) {
                acc1[a] = __builtin_amdgcn_mfma_f32_16x16x32_f16(wh[a][kt], dh[kt], acc1[a], 0, 0, 0);
                acc2[a] = __builtin_amdgcn_mfma_f32_16x16x32_f16(wl[a][kt], dh[kt], acc2[a], 0, 0, 0);
            }
        cur ^= 1;
    }

    // --- share z across waves: znb[sample][row]
    if (n < 4) {
        #pragma unroll
        for (int a = 0; a < 4; ++a) {
            float4 v = make_float4(znv[a][0], znv[a][1], znv[a][2], znv[a][3]);
            *(float4*)&znb[n][64 * w + 16 * a + 4 * kg] = v;
        }
    }
    __syncthreads();

    // --- per-wave solve: wave w handles sample s0+w (barrier-free, wave-local)
    const int sample = s0 + w;
    const float4 zz = *(const float4*)&znb[w][4 * l];
    const int c0 = zz.x != 0.f, c1 = zz.y != 0.f, c2 = zz.z != 0.f, c3 = zz.w != 0.f;
    const int cnt = c0 + c1 + c2 + c3;
    int scan = cnt;
    for (int d = 1; d < 64; d <<= 1) {
        const int v = __shfl_up(scan, d);
        if (l >= d) scan += v;
    }
    int o = scan - cnt;
    const int k = __shfl(scan, 63);

    if (k == 0) {
        if (l == 0) {
            kflag[sample] = 0;
            out[sample * 2] = 0.f;
            out[sample * 2 + 1] = 0.f;
        }
        return;
    }
    if (k > KS) {
        if (l == 0) kflag[sample] = 1;
        #pragma unroll
        for (int q = 0; q < 4; ++q)
            zbuf[sample * 256 + 4 * l + q] = ((const float*)&zz)[q];
        return;
    }
    if (l == 0) kflag[sample] = 0;

    if (c0) { idxs[w][o] = 4 * l + 0; sgns[w][o] = zz.x > 0.f ? 1.f : -1.f; ++o; }
    if (c1) { idxs[w][o] = 4 * l + 1; sgns[w][o] = zz.y > 0.f ? 1.f : -1.f; ++o; }
    if (c2) { idxs[w][o] = 4 * l + 2; sgns[w][o] = zz.z > 0.f ? 1.f : -1.f; ++o; }
    if (c3) { idxs[w][o] = 4 * l + 3; sgns[w][o] = zz.w > 0.f ? 1.f : -1.f; ++o; }

    const int   ib = idxs[w][(l < k) ? l : (k - 1)];
    const float sg = (l < k) ? sgns[w][l] : 0.f;
    float rhs = (l < k) ? (cbuf[sample * 256 + ib] - LAMBD * sg) : 0.f;

    for (int a = 0; a < k; ++a) {
        const int ra = __shfl(ib, a);
        if (l < k) Gm[w][a * (KS + 1) + l] = Gfull[ra * 256 + ib];
    }

    float dinv = 0.f;
    for (int j = 0; j < k; ++j) {
        const float Gjj = Gm[w][j * (KS + 1) + j];
        const float Ljj = sqrtf(fmaxf(Gjj, 1e-30f));
        const float iv = 1.0f / Ljj;
        float Laj = 0.f;
        if (l == j) { Gm[w][j * (KS + 1) + j] = Ljj; dinv = iv; }
        if (l > j && l < k) { Laj = Gm[w][l * (KS + 1) + j] * iv; Gm[w][l * (KS + 1) + j] = Laj; }
        for (int b = j + 1; b < k; ++b) {
            const float Lbj = Gm[w][b * (KS + 1) + j];
            if (l >= b && l < k) Gm[w][l * (KS + 1) + b] -= Laj * Lbj;
        }
    }

    float y = rhs;
    for (int j = 0; j < k; ++j) {
        const float Laj = Gm[w][l * (KS + 1) + j];
        const float yjf = __shfl(y, j) * __shfl(dinv, j);
        if (l == j) y = yjf;
        if (l > j) y -= Laj * yjf;
    }
    float xv = y;
    for (int j = k - 1; j >= 0; --j) {
        const float Lja = Gm[w][j * (KS + 1) + l];
        const float xjf = __shfl(xv, j) * __shfl(dinv, j);
        if (l == j) xv = xjf;
        if (l < j) xv -= Lja * xjf;
    }

    float acc = (l < k) ? wg[ib] * xv : 0.f;
    for (int d = 1; d < 64; d <<= 1) acc += __shfl_xor(acc, d);
    if (l == 0) { out[sample * 2] = acc; out[sample * 2 + 1] = -acc; }
}

// ---------------- Kernel 3: k > 64 fallback (flag-gated, usually no-op) ----------------
__global__ __launch_bounds__(64) void solve_big(const float* __restrict__ Gfull,
                                                const float* __restrict__ cbuf,
                                                const float* __restrict__ wg,
                                                const float* __restrict__ zbuf,
                                                const int* __restrict__ kflag,
                                                float* __restrict__ out)
{
    __shared__ __align__(16) float Gm[KMAX * (KMAX + 1)];
    __shared__ int   idx[KMAX];
    __shared__ float sgn[KMAX];
    __shared__ float rhs[KMAX];
    __shared__ float sol[KMAX];

    const int l = threadIdx.x;
    const int sample = blockIdx.x;
    if (!kflag[sample]) return;

    const float4 zz = ((const float4*)(zbuf + sample * 256))[l];
    const int c0 = zz.x != 0.f, c1 = zz.y != 0.f, c2 = zz.z != 0.f, c3 = zz.w != 0.f;
    const int cnt = c0 + c1 + c2 + c3;
    int scan = cnt;
    for (int d = 1; d < 64; d <<= 1) {
        const int v = __shfl_up(scan, d);
        if (l >= d) scan += v;
    }
    int o = scan - cnt;
    int k = __shfl(scan, 63);
    if (k > KMAX) k = KMAX;
    if (c0) { if (o < KMAX) { idx[o] = 4 * l + 0; sgn[o] = zz.x > 0.f ? 1.f : -1.f; } ++o; }
    if (c1) { if (o < KMAX) { idx[o] = 4 * l + 1; sgn[o] = zz.y > 0.f ? 1.f : -1.f; } ++o; }
    if (c2) { if (o < KMAX) { idx[o] = 4 * l + 2; sgn[o] = zz.z > 0.f ? 1.f : -1.f; } ++o; }
    if (c3) { if (o < KMAX) { idx[o] = 4 * l + 3; sgn[o] = zz.w > 0.f ? 1.f : -1.f; } ++o; }
    __syncthreads();

    for (int a = 0; a < k; ++a) {
        const int ra = idx[a];
        for (int b = l; b < k; b += 64)
            Gm[a * (KMAX + 1) + b] = Gfull[ra * 256 + idx[b]];
    }
    for (int a = l; a < k; a += 64)
        rhs[a] = cbuf[sample * 256 + idx[a]] - LAMBD * sgn[a];
    __syncthreads();

    for (int j = 0; j < k; ++j) {
        const float Ljj = sqrtf(fmaxf(Gm[j * (KMAX + 1) + j], 1e-30f));
        const float inv = 1.0f / Ljj;
        if (l == 0) Gm[j * (KMAX + 1) + j] = Ljj;
        for (int a = j + 1 + l; a < k; a += 64)
            Gm[a * (KMAX + 1) + j] *= inv;
        __syncthreads();
        for (int b = j + 1; b < k; ++b) {
            const float Lbj = Gm[b * (KMAX + 1) + j];
            for (int a = b + l; a < k; a += 64)
                Gm[a * (KMAX + 1) + b] -= Gm[a * (KMAX + 1) + j] * Lbj;
        }
        __syncthreads();
    }
    for (int j = 0; j < k; ++j) {
        const float yj = rhs[j] / Gm[j * (KMAX + 1) + j];
        if (l == 0) sol[j] = yj;
        for (int a = j + 1 + l; a < k; a += 64)
            rhs[a] -= Gm[a * (KMAX + 1) + j] * yj;
        __syncthreads();
    }
    for (int j = k - 1; j >= 0; --j) {
        const float xj = sol[j] / Gm[j * (KMAX + 1) + j];
        if (l == 0) sol[j] = xj;
        for (int a = l; a < j; a += 64)
            sol[a] -= Gm[j * (KMAX + 1) + a] * xj;
        __syncthreads();
    }
    float acc = 0.f;
    for (int a = l; a < k; a += 64)
        acc += wg[idx[a]] * sol[a];
    for (int d = 1; d < 64; d <<= 1) acc += __shfl_xor(acc, d);
    if (l == 0) { out[sample * 2] = acc; out[sample * 2 + 1] = -acc; }
}

extern "C" void kernel_launch(void* const* d_in, const int* in_sizes, int n_in,
                              void* d_out, int out_size, void* d_ws, size_t ws_size,
                              hipStream_t stream) {
    const float* x = (const float*)d_in[0];   // (1024, 64)
    const float* D = (const float*)d_in[1];   // (64, 256)
    const float* w = (const float*)d_in[2];   // (256,)
    float* out = (float*)d_out;               // (1024, 2)
    float* ws  = (float*)d_ws;

    float* Gfull = ws + 256;                        // 65536 floats
    float* zbuf  = ws + 256 + 65536;                // 262144 floats (k>64 path only)
    float* cbuf  = ws + 256 + 65536 + 262144;       // 262144 floats
    int*   kflag = (int*)(ws + 256 + 65536 + 262144 + 262144);  // 1024 ints

    prep_all<<<257, 256, 0, stream>>>(x, D, ws, Gfull, cbuf);
    ista_solve<<<256, 256, 0, stream>>>(cbuf, Gfull, ws, w, zbuf, kflag, out);
    solve_big<<<1024, 64, 0, stream>>>(Gfull, cbuf, w, zbuf, kflag, out);
}

// Round 7
// 237.526 us; speedup vs baseline: 9.4467x; 1.0260x over previous
//
#include <hip/hip_runtime.h>

#define LAMBD 0.2f
#define KMAX 128
#define KS 64

using half8 = __attribute__((ext_vector_type(8))) _Float16;
using f32x4 = __attribute__((ext_vector_type(4))) float;

__device__ __forceinline__ float sshrink(float v, float thr) {
    float c = fminf(fmaxf(v, -thr), thr);
    return v - c;
}

__device__ __forceinline__ unsigned pack2(_Float16 a, _Float16 b) {
    unsigned short ua = __builtin_bit_cast(unsigned short, a);
    unsigned short ub = __builtin_bit_cast(unsigned short, b);
    return (unsigned)ua | ((unsigned)ub << 16);
}

// ---------------- Kernel 1: fused prep. Block 0: s = 1/sigma_max(D)^2 (power iter).
// Blocks 1..256: Gram row r + cbuf = D^T x.
__global__ __launch_bounds__(256) void prep_all(const float* __restrict__ xg,
                                                const float* __restrict__ Dg,
                                                float* __restrict__ ws,
                                                float* __restrict__ Gfull,
                                                float* __restrict__ cbuf)
{
    const int t = threadIdx.x;
    if (blockIdx.x == 0) {
        __shared__ __align__(16) float Dc[256 * 68];
        __shared__ __align__(16) float Bm[64 * 68];
        __shared__ float vv[64];
        __shared__ float part[4 * 64];
        __shared__ float lamsh;

        for (int i = 0; i < 64; ++i)
            Dc[t * 68 + i] = Dg[i * 256 + t];
        __syncthreads();

        const int ti = t >> 4, tj = t & 15;
        float acc[4][4];
        #pragma unroll
        for (int r = 0; r < 4; ++r)
            #pragma unroll
            for (int c = 0; c < 4; ++c) acc[r][c] = 0.f;
        for (int mm = 0; mm < 256; ++mm) {
            const float4 A = *(const float4*)&Dc[mm * 68 + 4 * ti];
            const float4 Bv = *(const float4*)&Dc[mm * 68 + 4 * tj];
            const float Ae[4] = {A.x, A.y, A.z, A.w};
            const float Be[4] = {Bv.x, Bv.y, Bv.z, Bv.w};
            #pragma unroll
            for (int r = 0; r < 4; ++r)
                #pragma unroll
                for (int c = 0; c < 4; ++c)
                    acc[r][c] += Ae[r] * Be[c];
        }
        #pragma unroll
        for (int r = 0; r < 4; ++r)
            #pragma unroll
            for (int c = 0; c < 4; ++c)
                Bm[(4 * ti + r) * 68 + (4 * tj + c)] = acc[r][c];
        if (t < 64) vv[t] = 0.125f;
        __syncthreads();

        for (int itp = 0; itp < 40; ++itp) {
            const int p = t >> 6, i = t & 63;
            float partial = 0.f;
            #pragma unroll
            for (int jj = 0; jj < 16; ++jj) {
                const int j = p * 16 + jj;
                partial += Bm[j * 68 + i] * vv[j];
            }
            part[p * 64 + i] = partial;
            __syncthreads();
            if (t < 64) {
                float nv = part[t] + part[64 + t] + part[128 + t] + part[192 + t];
                float n2 = nv * nv;
                for (int d = 1; d < 64; d <<= 1) n2 += __shfl_xor(n2, d);
                vv[t] = nv * rsqrtf(n2);
                if (t == 0) lamsh = n2;
            }
            __syncthreads();
        }
        if (t == 0) ws[0] = 1.0f / sqrtf(lamsh);   // s = 1/lambda_max(B)  (FISTA-safe)
    } else {
        __shared__ float xsh[4][64];
        const int r = blockIdx.x - 1;
        const int s0 = r * 4;
        xsh[t >> 6][t & 63] = xg[s0 * 64 + t];
        __syncthreads();

        float accG = 0.f, a0 = 0.f, a1 = 0.f, a2 = 0.f, a3 = 0.f;
        #pragma unroll
        for (int i = 0; i < 64; ++i) {
            const float dv = Dg[i * 256 + t];
            const float dr = Dg[i * 256 + r];
            accG += dr * dv;
            a0 += xsh[0][i] * dv;
            a1 += xsh[1][i] * dv;
            a2 += xsh[2][i] * dv;
            a3 += xsh[3][i] * dv;
        }
        Gfull[r * 256 + t] = accG;
        cbuf[(s0 + 0) * 256 + t] = a0;
        cbuf[(s0 + 1) * 256 + t] = a1;
        cbuf[(s0 + 2) * 256 + t] = a2;
        cbuf[(s0 + 3) * 256 + t] = a3;
    }
}

// ---------------- Kernel 2: FISTA (MFMA delta-y) + per-wave solve + in-block big-k ------
__global__ __launch_bounds__(256, 1) void ista_solve(const float* __restrict__ cbuf,
                                                     const float* __restrict__ Gfull,
                                                     const float* __restrict__ ws,
                                                     const float* __restrict__ wg,
                                                     float* __restrict__ out)
{
    __shared__ __align__(16) _Float16 dbuf[2][16][264];
    __shared__ int chgs[4];
    __shared__ __align__(16) float znb[4][264];      // [sample][row]
    __shared__ __align__(16) float GmPool[16640];    // 4 x KS*(KS+1) | KMAX*(KMAX+1)
    __shared__ int   idxPool[256];                   // 4 x KS | KMAX
    __shared__ float sgnPool[256];
    __shared__ float rhsF[KMAX];
    __shared__ float solF[KMAX];
    __shared__ int   big4[4];
    __shared__ int   kbig;

    const int t = threadIdx.x;
    const int w = t >> 6, l = t & 63;
    const int n = l & 15, kg = l >> 4;
    const int s0 = blockIdx.x * 4;
    const float s = ws[0];
    const float thr = LAMBD * s;
    const float S = 1.0f / 2048.0f;
    const float FLUSH = 6.2e-5f;

    // --- build W = I - s*G fragments from Gfull (fp32 -> f16 hi/lo)
    half8 wh[4][8], wl[4][8];
    #pragma unroll
    for (int a = 0; a < 4; ++a) {
        const int row = 64 * w + 16 * a + n;
        #pragma unroll
        for (int kt = 0; kt < 8; ++kt) {
            const float4 g0 = *(const float4*)&Gfull[row * 256 + kt * 32 + kg * 8];
            const float4 g1 = *(const float4*)&Gfull[row * 256 + kt * 32 + kg * 8 + 4];
            const float ge[8] = {g0.x, g0.y, g0.z, g0.w, g1.x, g1.y, g1.z, g1.w};
            half8 h, lo;
            #pragma unroll
            for (int j = 0; j < 8; ++j) {
                const int col = kt * 32 + kg * 8 + j;
                const float wv = (row == col ? 1.0f : 0.0f) - s * ge[j];
                const _Float16 whj = (_Float16)wv;
                h[j] = whj;
                lo[j] = (_Float16)((wv - (float)whj) * 2048.0f);
            }
            wh[a][kt] = h;
            wl[a][kt] = lo;
        }
    }

    // --- state: y = sum of f16 deltas (drives P); z_old, z_new f32; b.
    float bv[4][4], y[4][4], zo[4][4], zn[4][4];
    #pragma unroll
    for (int a = 0; a < 4; ++a)
        #pragma unroll
        for (int jj = 0; jj < 4; ++jj) {
            const int row = 64 * w + 16 * a + 4 * kg + jj;
            bv[a][jj] = (n < 4) ? s * cbuf[(s0 + n) * 256 + row] : 0.f;
            y[a][jj] = 0.f;
            zo[a][jj] = 0.f;
        }

    f32x4 acc1[4], acc2[4];
    #pragma unroll
    for (int a = 0; a < 4; ++a) {
        acc1[a] = (f32x4){0.f, 0.f, 0.f, 0.f};
        acc2[a] = (f32x4){0.f, 0.f, 0.f, 0.f};
    }

    float tk = 1.0f;
    int cur = 0;
    for (int it = 0; ; ++it) {
        // z_new = ssh(W y + b);  y_new = z_new + beta (z_new - z_old)
        const float tk1 = 0.5f * (1.0f + sqrtf(1.0f + 4.0f * tk * tk));
        const float beta = (tk - 1.0f) / tk1;
        bool anyflag = false;
        _Float16 dh16[4][4];
        #pragma unroll
        for (int a = 0; a < 4; ++a)
            #pragma unroll
            for (int jj = 0; jj < 4; ++jj) {
                const float P = acc1[a][jj] + S * acc2[a][jj];
                const float z = sshrink(P + bv[a][jj], thr);
                zn[a][jj] = z;
                const float yn = z + beta * (z - zo[a][jj]);
                zo[a][jj] = z;
                const float d = yn - y[a][jj];
                const bool live = fabsf(d) >= FLUSH;
                anyflag |= live;
                const _Float16 hd = live ? (_Float16)d : (_Float16)0.0f;
                dh16[a][jj] = hd;
                y[a][jj] += (float)hd;
            }
        tk = tk1;
        if (it == 1000) break;

        const int anyw = __any(anyflag);
        if (l == 0) chgs[w] = anyw;
        #pragma unroll
        for (int a = 0; a < 4; ++a) {
            const unsigned lo = pack2(dh16[a][0], dh16[a][1]);
            const unsigned hi = pack2(dh16[a][2], dh16[a][3]);
            *(uint2*)&dbuf[cur][n][64 * w + 16 * a + 4 * kg] = make_uint2(lo, hi);
        }
        __syncthreads();
        if (!(chgs[0] | chgs[1] | chgs[2] | chgs[3])) break;   // y frozen -> converged

        half8 dh[8];
        #pragma unroll
        for (int kt = 0; kt < 8; ++kt)
            dh[kt] = *(const half8*)&dbuf[cur][n][kt * 32 + kg * 8];

        #pragma unroll
        for (int kt = 0; kt < 8; ++kt)
            #pragma unroll
            for (int a = 0; a < 4; ++a) {
                acc1[a] = __builtin_amdgcn_mfma_f32_16x16x32_f16(wh[a][kt], dh[kt], acc1[a], 0, 0, 0);
                acc2[a] = __builtin_amdgcn_mfma_f32_16x16x32_f16(wl[a][kt], dh[kt], acc2[a], 0, 0, 0);
            }
        cur ^= 1;
    }

    // --- share z (z_new) across waves
    if (n < 4) {
        #pragma unroll
        for (int a = 0; a < 4; ++a) {
            float4 v = make_float4(zn[a][0], zn[a][1], zn[a][2], zn[a][3]);
            *(float4*)&znb[n][64 * w + 16 * a + 4 * kg] = v;
        }
    }
    __syncthreads();

    // --- per-wave solve: wave w handles sample s0+w
    const int sample = s0 + w;
    float* Gw = GmPool + w * (KS * (KS + 1));
    int*   idxW = idxPool + w * KS;
    float* sgnW = sgnPool + w * KS;

    const float4 zz = *(const float4*)&znb[w][4 * l];
    const int c0 = zz.x != 0.f, c1 = zz.y != 0.f, c2 = zz.z != 0.f, c3 = zz.w != 0.f;
    const int cnt = c0 + c1 + c2 + c3;
    int scan = cnt;
    for (int d = 1; d < 64; d <<= 1) {
        const int v = __shfl_up(scan, d);
        if (l >= d) scan += v;
    }
    int o = scan - cnt;
    const int k = __shfl(scan, 63);
    if (l == 0) big4[w] = (k > KS) ? 1 : 0;

    if (k == 0) {
        if (l == 0) { out[sample * 2] = 0.f; out[sample * 2 + 1] = 0.f; }
    } else if (k <= KS) {
        if (c0) { idxW[o] = 4 * l + 0; sgnW[o] = zz.x > 0.f ? 1.f : -1.f; ++o; }
        if (c1) { idxW[o] = 4 * l + 1; sgnW[o] = zz.y > 0.f ? 1.f : -1.f; ++o; }
        if (c2) { idxW[o] = 4 * l + 2; sgnW[o] = zz.z > 0.f ? 1.f : -1.f; ++o; }
        if (c3) { idxW[o] = 4 * l + 3; sgnW[o] = zz.w > 0.f ? 1.f : -1.f; ++o; }
        __builtin_amdgcn_wave_barrier();

        const int   ib = idxW[(l < k) ? l : (k - 1)];
        const float sg = (l < k) ? sgnW[l] : 0.f;
        float rhs = (l < k) ? (cbuf[sample * 256 + ib] - LAMBD * sg) : 0.f;

        for (int a = 0; a < k; ++a) {
            const int ra = __shfl(ib, a);
            if (l < k) Gw[a * (KS + 1) + l] = Gfull[ra * 256 + ib];
        }
        __builtin_amdgcn_wave_barrier();

        float dinv = 0.f;
        for (int j = 0; j < k; ++j) {
            const float Gjj = Gw[j * (KS + 1) + j];
            const float Ljj = sqrtf(fmaxf(Gjj, 1e-30f));
            const float iv = 1.0f / Ljj;
            float Laj = 0.f;
            if (l == j) { Gw[j * (KS + 1) + j] = Ljj; dinv = iv; }
            if (l > j && l < k) { Laj = Gw[l * (KS + 1) + j] * iv; Gw[l * (KS + 1) + j] = Laj; }
            __builtin_amdgcn_wave_barrier();
            for (int b = j + 1; b < k; ++b) {
                const float Lbj = Gw[b * (KS + 1) + j];
                if (l >= b && l < k) Gw[l * (KS + 1) + b] -= Laj * Lbj;
            }
            __builtin_amdgcn_wave_barrier();
        }

        float yv = rhs;
        for (int j = 0; j < k; ++j) {
            const float Laj = Gw[l * (KS + 1) + j];
            const float yjf = __shfl(yv, j) * __shfl(dinv, j);
            if (l == j) yv = yjf;
            if (l > j) yv -= Laj * yjf;
        }
        float xv = yv;
        for (int j = k - 1; j >= 0; --j) {
            const float Lja = Gw[j * (KS + 1) + l];
            const float xjf = __shfl(xv, j) * __shfl(dinv, j);
            if (l == j) xv = xjf;
            if (l < j) xv -= Lja * xjf;
        }

        float acc = (l < k) ? wg[ib] * xv : 0.f;
        for (int d = 1; d < 64; d <<= 1) acc += __shfl_xor(acc, d);
        if (l == 0) { out[sample * 2] = acc; out[sample * 2 + 1] = -acc; }
    }
    __syncthreads();

    // --- rare big-k path: block-cooperative, sequential over flagged samples
    for (int sw = 0; sw < 4; ++sw) {
        if (!big4[sw]) continue;                       // uniform (LDS)
        const int smp = s0 + sw;
        if (w == 0) {
            const float4 z2 = *(const float4*)&znb[sw][4 * l];
            const int d0 = z2.x != 0.f, d1 = z2.y != 0.f, d2 = z2.z != 0.f, d3 = z2.w != 0.f;
            const int cn = d0 + d1 + d2 + d3;
            int sc = cn;
            for (int d = 1; d < 64; d <<= 1) {
                const int v = __shfl_up(sc, d);
                if (l >= d) sc += v;
            }
            int oo = sc - cn;
            int kk = __shfl(sc, 63);
            if (kk > KMAX) kk = KMAX;
            if (l == 0) kbig = kk;
            if (d0) { if (oo < KMAX) { idxPool[oo] = 4 * l + 0; sgnPool[oo] = z2.x > 0.f ? 1.f : -1.f; } ++oo; }
            if (d1) { if (oo < KMAX) { idxPool[oo] = 4 * l + 1; sgnPool[oo] = z2.y > 0.f ? 1.f : -1.f; } ++oo; }
            if (d2) { if (oo < KMAX) { idxPool[oo] = 4 * l + 2; sgnPool[oo] = z2.z > 0.f ? 1.f : -1.f; } ++oo; }
            if (d3) { if (oo < KMAX) { idxPool[oo] = 4 * l + 3; sgnPool[oo] = z2.w > 0.f ? 1.f : -1.f; } ++oo; }
        }
        __syncthreads();
        const int kk = kbig;
        float* Gb = GmPool;

        for (int a = 0; a < kk; ++a) {
            const int ra = idxPool[a];
            for (int b = t; b < kk; b += 256)
                Gb[a * (KMAX + 1) + b] = Gfull[ra * 256 + idxPool[b]];
        }
        for (int a = t; a < kk; a += 256)
            rhsF[a] = cbuf[smp * 256 + idxPool[a]] - LAMBD * sgnPool[a];
        __syncthreads();

        for (int j = 0; j < kk; ++j) {
            const float Ljj = sqrtf(fmaxf(Gb[j * (KMAX + 1) + j], 1e-30f));
            const float inv = 1.0f / Ljj;
            if (t == 0) Gb[j * (KMAX + 1) + j] = Ljj;
            for (int a = j + 1 + t; a < kk; a += 256)
                Gb[a * (KMAX + 1) + j] *= inv;
            __syncthreads();
            for (int b = j + 1; b < kk; ++b) {
                const float Lbj = Gb[b * (KMAX + 1) + j];
                const int a = b + t;
                if (a < kk) Gb[a * (KMAX + 1) + b] -= Gb[a * (KMAX + 1) + j] * Lbj;
            }
            __syncthreads();
        }
        for (int j = 0; j < kk; ++j) {
            const float yj = rhsF[j] / Gb[j * (KMAX + 1) + j];
            if (t == 0) solF[j] = yj;
            for (int a = j + 1 + t; a < kk; a += 256)
                rhsF[a] -= Gb[a * (KMAX + 1) + j] * yj;
            __syncthreads();
        }
        for (int j = kk - 1; j >= 0; --j) {
            const float xj = solF[j] / Gb[j * (KMAX + 1) + j];
            if (t == 0) solF[j] = xj;
            for (int a = t; a < j; a += 256)
                solF[a] -= Gb[j * (KMAX + 1) + a] * xj;
            __syncthreads();
        }
        float acc = 0.f;
        for (int a = t; a < kk; a += 256)
            acc += wg[idxPool[a]] * solF[a];
        for (int d = 1; d < 64; d <<= 1) acc += __shfl_xor(acc, d);
        if (l == 0) atomicAdd(&solF[0], 0.f);   // no-op keep
        // block reduce via LDS (reuse rhsF)
        if (l == 0) rhsF[64 + w] = acc;
        __syncthreads();
        if (t == 0) {
            const float tot = rhsF[64] + rhsF[65] + rhsF[66] + rhsF[67];
            out[smp * 2] = tot;
            out[smp * 2 + 1] = -tot;
        }
        __syncthreads();
    }
}

extern "C" void kernel_launch(void* const* d_in, const int* in_sizes, int n_in,
                              void* d_out, int out_size, void* d_ws, size_t ws_size,
                              hipStream_t stream) {
    const float* x = (const float*)d_in[0];   // (1024, 64)
    const float* D = (const float*)d_in[1];   // (64, 256)
    const float* w = (const float*)d_in[2];   // (256,)
    float* out = (float*)d_out;               // (1024, 2)
    float* ws  = (float*)d_ws;

    float* Gfull = ws + 256;                  // 65536 floats
    float* cbuf  = ws + 256 + 65536;          // 262144 floats

    prep_all<<<257, 256, 0, stream>>>(x, D, ws, Gfull, cbuf);
    ista_solve<<<256, 256, 0, stream>>>(cbuf, Gfull, ws, w, out);
}